// Round 1
// baseline (14421.443 us; speedup 1.0000x reference)
//
#include <hip/hip_runtime.h>
#include <hip/hip_bf16.h>

#define B 32
#define S 512
#define E 512
#define H 512
#define NH 8
#define HD 64
#define QT 16

// ---------------- GEMM: C[M,N] = A[M,K] @ W[N,K]^T + bias[N] ----------------
// BM=BN=64, BK=16, 256 threads, 4x4 microtile. Requires M%64==0, N%64==0, K%16==0.
// mode 0: C[r*N+c].  mode 1: scatter rows r=b*S+s -> C[(s*B+b)*N+c] (RNN time-major).
__global__ __launch_bounds__(256) void gemm_bias(const float* __restrict__ A,
                                                 const float* __restrict__ W,
                                                 const float* __restrict__ bias,
                                                 float* __restrict__ C,
                                                 int M, int N, int K, int mode) {
    __shared__ float As[16][68];
    __shared__ float Ws[16][68];
    int t = threadIdx.x;
    int n0 = blockIdx.x * 64;
    int m0 = blockIdx.y * 64;
    int ty = t >> 4, tx = t & 15;
    int lr = t >> 2;          // 0..63
    int lc = (t & 3) * 4;     // 0,4,8,12
    float acc[4][4] = {};
    for (int k0 = 0; k0 < K; k0 += 16) {
        float4 av = *(const float4*)&A[(size_t)(m0 + lr) * K + k0 + lc];
        float4 wv = *(const float4*)&W[(size_t)(n0 + lr) * K + k0 + lc];
        As[lc + 0][lr] = av.x; As[lc + 1][lr] = av.y; As[lc + 2][lr] = av.z; As[lc + 3][lr] = av.w;
        Ws[lc + 0][lr] = wv.x; Ws[lc + 1][lr] = wv.y; Ws[lc + 2][lr] = wv.z; Ws[lc + 3][lr] = wv.w;
        __syncthreads();
#pragma unroll
        for (int kk = 0; kk < 16; ++kk) {
            float4 a = *(const float4*)&As[kk][ty * 4];
            float4 b = *(const float4*)&Ws[kk][tx * 4];
            float ar[4] = {a.x, a.y, a.z, a.w};
            float br[4] = {b.x, b.y, b.z, b.w};
#pragma unroll
            for (int i = 0; i < 4; ++i)
#pragma unroll
                for (int j = 0; j < 4; ++j) acc[i][j] += ar[i] * br[j];
        }
        __syncthreads();
    }
    int c = n0 + tx * 4;
#pragma unroll
    for (int i = 0; i < 4; ++i) {
        int r = m0 + ty * 4 + i;
        size_t rowbase;
        if (mode == 0) rowbase = (size_t)r * N;
        else { int b_ = r / S, s_ = r % S; rowbase = (size_t)(s_ * B + b_) * N; }
        float4 o;
        o.x = acc[i][0] + bias[c + 0];
        o.y = acc[i][1] + bias[c + 1];
        o.z = acc[i][2] + bias[c + 2];
        o.w = acc[i][3] + bias[c + 3];
        *(float4*)&C[rowbase + c] = o;
    }
}

// ---------------- Attention: per (b, h, 16-row q-tile). ctx overwrites Q in place. ----
__global__ __launch_bounds__(256) void attn_kernel(float* __restrict__ Q,
                                                   const float* __restrict__ K,
                                                   const float* __restrict__ V) {
    __shared__ float QsT[64][QT + 1];   // [d][q]
    __shared__ float KVs[64][65];       // [k][d] staging for K then V tiles
    __shared__ float sc[512][QT];       // [k][q] scores
    __shared__ float red[16][QT];
    __shared__ float mx[QT], sminv[QT];
    int t = threadIdx.x;
    int bid = blockIdx.x;
    int qt = bid & 31;            // 32 q-tiles of 16
    int h = (bid >> 5) & 7;
    int b = bid >> 8;
    const int qbase = b * S + qt * QT;
    const int col0 = h * HD;
    // stage Q^T
#pragma unroll
    for (int i = 0; i < 4; ++i) {
        int e = t + i * 256;
        int q = e >> 6, d = e & 63;
        QsT[d][q] = Q[(size_t)(qbase + q) * E + col0 + d];
    }
    int q = t & (QT - 1);
    int g = t >> 4;               // 0..15
    float lmax = -1e30f;
    for (int kt = 0; kt < 8; ++kt) {
        __syncthreads();
#pragma unroll
        for (int i = 0; i < 16; ++i) {
            int e = t + i * 256;
            int k = e >> 6, d = e & 63;
            KVs[k][d] = K[(size_t)(b * S + kt * 64 + k) * E + col0 + d];
        }
        __syncthreads();
#pragma unroll
        for (int kk = 0; kk < 4; ++kk) {
            int kl = g * 4 + kk;
            float s = 0.f;
#pragma unroll
            for (int d = 0; d < 64; ++d) s += QsT[d][q] * KVs[kl][d];
            s *= 0.125f;  // 1/sqrt(64)
            sc[kt * 64 + kl][q] = s;
            lmax = fmaxf(lmax, s);
        }
    }
    red[g][q] = lmax;
    __syncthreads();
    if (t < QT) {
        float m = red[0][t];
#pragma unroll
        for (int i = 1; i < 16; ++i) m = fmaxf(m, red[i][t]);
        mx[t] = m;
    }
    __syncthreads();
    float m = mx[q];
    float lsum = 0.f;
#pragma unroll
    for (int i = 0; i < 32; ++i) {
        int k = g * 32 + i;
        float e = __expf(sc[k][q] - m);
        sc[k][q] = e;
        lsum += e;
    }
    red[g][q] = lsum;
    __syncthreads();
    if (t < QT) {
        float s2 = 0.f;
#pragma unroll
        for (int i = 0; i < 16; ++i) s2 += red[i][t];
        sminv[t] = 1.0f / s2;
    }
    // PV
    float ctx[4] = {0.f, 0.f, 0.f, 0.f};
    int dp = g;
    for (int kt = 0; kt < 8; ++kt) {
        __syncthreads();
#pragma unroll
        for (int i = 0; i < 16; ++i) {
            int e = t + i * 256;
            int k = e >> 6, d = e & 63;
            KVs[k][d] = V[(size_t)(b * S + kt * 64 + k) * E + col0 + d];
        }
        __syncthreads();
        for (int kk = 0; kk < 64; ++kk) {
            float p = sc[kt * 64 + kk][q];
#pragma unroll
            for (int jj = 0; jj < 4; ++jj) ctx[jj] += p * KVs[kk][dp * 4 + jj];
        }
    }
    float inv = sminv[q];
    float4 o;
    o.x = ctx[0] * inv; o.y = ctx[1] * inv; o.z = ctx[2] * inv; o.w = ctx[3] * inv;
    *(float4*)&Q[(size_t)(qbase + q) * E + col0 + dp * 4] = o;
}

// ---------------- 512x512 transpose (for Whh -> k-major) ----------------
__global__ __launch_bounds__(256) void transpose512(const float* __restrict__ Wm,
                                                    float* __restrict__ WT) {
    __shared__ float tile[32][33];
    int bx = blockIdx.x & 15;
    int by = blockIdx.x >> 4;
    int tx = threadIdx.x & 31;
    int ty = threadIdx.x >> 5;  // 0..7
#pragma unroll
    for (int i = 0; i < 4; ++i) {
        int j = ty + i * 8;
        tile[j][tx] = Wm[(size_t)(by * 32 + j) * 512 + bx * 32 + tx];
    }
    __syncthreads();
#pragma unroll
    for (int i = 0; i < 4; ++i) {
        int k = ty + i * 8;
        WT[(size_t)(bx * 32 + k) * 512 + by * 32 + tx] = tile[tx][k];
    }
}

// ---------------- one RNN recurrence step: h = tanh(pre + hprev @ Whh^T) --------------
// WT is Whh transposed: WT[k][j] = Whh[j][k]. pre already includes bih + x@Wih^T.
__global__ __launch_bounds__(64) void rnn_step(const float* __restrict__ pre,
                                               const float* __restrict__ hprev,
                                               float* __restrict__ hout,
                                               const float* __restrict__ WT,
                                               const float* __restrict__ bhh,
                                               int first) {
    int tid = blockIdx.x * 64 + threadIdx.x;
    int j = tid & 511;
    int b = tid >> 9;
    float acc = pre[b * 512 + j] + bhh[j];
    if (!first) {
        const float* hr = hprev + b * 512;
        float a0 = 0.f, a1 = 0.f, a2 = 0.f, a3 = 0.f;
#pragma unroll 4
        for (int k = 0; k < 512; k += 4) {
            a0 += hr[k + 0] * WT[(k + 0) * 512 + j];
            a1 += hr[k + 1] * WT[(k + 1) * 512 + j];
            a2 += hr[k + 2] * WT[(k + 2) * 512 + j];
            a3 += hr[k + 3] * WT[(k + 3) * 512 + j];
        }
        acc += (a0 + a1) + (a2 + a3);
    }
    hout[b * 512 + j] = tanhf(acc);
}

// ---------------- final FC: out[b] = h[b,:] . Wfc[0,:] + bfc[0] ----------------
__global__ __launch_bounds__(64) void fc_out(const float* __restrict__ h,
                                             const float* __restrict__ Wfc,
                                             const float* __restrict__ bfc,
                                             float* __restrict__ out) {
    int b = blockIdx.x;
    int t = threadIdx.x;
    float a = 0.f;
    for (int j = t; j < 512; j += 64) a += h[b * 512 + j] * Wfc[j];
#pragma unroll
    for (int o = 32; o; o >>= 1) a += __shfl_down(a, o, 64);
    if (t == 0) out[b] = a + bfc[0];
}

extern "C" void kernel_launch(void* const* d_in, const int* in_sizes, int n_in,
                              void* d_out, int out_size, void* d_ws, size_t ws_size,
                              hipStream_t stream) {
    const float* x   = (const float*)d_in[0];
    const float* Wq  = (const float*)d_in[1];
    const float* bq  = (const float*)d_in[2];
    const float* Wk  = (const float*)d_in[3];
    const float* bk  = (const float*)d_in[4];
    const float* Wv  = (const float*)d_in[5];
    const float* bv  = (const float*)d_in[6];
    const float* Wo  = (const float*)d_in[7];
    const float* bo  = (const float*)d_in[8];
    const float* Wih = (const float*)d_in[9];
    const float* bih = (const float*)d_in[10];
    const float* Whh = (const float*)d_in[11];
    const float* bhh = (const float*)d_in[12];
    const float* Wfc = (const float*)d_in[13];
    const float* bfc = (const float*)d_in[14];
    float* out = (float*)d_out;
    float* ws = (float*)d_ws;

    float* Qb  = ws;                                  // 8M floats: Q -> ctx -> pre1[t][b][j]
    float* Kb  = ws + (size_t)8 * 1024 * 1024;        // 8M: K -> atten_out -> H0[t][b][j]
    float* Vb  = ws + (size_t)16 * 1024 * 1024;       // 8M: V -> pre0[t][b][j]
    float* WT0 = ws + (size_t)24 * 1024 * 1024;       // 256K
    float* WT1 = WT0 + 512 * 512;                     // 256K
    float* h1a = WT1 + 512 * 512;                     // 16K
    float* h1b = h1a + B * H;                         // 16K

    dim3 blk(256);
    dim3 g_gemm(E / 64, (B * S) / 64);

    // QKV projections
    gemm_bias<<<g_gemm, blk, 0, stream>>>(x, Wq, bq, Qb, B * S, E, E, 0);
    gemm_bias<<<g_gemm, blk, 0, stream>>>(x, Wk, bk, Kb, B * S, E, E, 0);
    gemm_bias<<<g_gemm, blk, 0, stream>>>(x, Wv, bv, Vb, B * S, E, E, 0);
    // attention (ctx -> Qb in place)
    attn_kernel<<<dim3(B * NH * (S / QT)), blk, 0, stream>>>(Qb, Kb, Vb);
    // output projection: atten_out -> Kb
    gemm_bias<<<g_gemm, blk, 0, stream>>>(Qb, Wo, bo, Kb, B * S, E, E, 0);
    // RNN layer-0 input preactivations, time-major: pre0 -> Vb
    gemm_bias<<<g_gemm, blk, 0, stream>>>(Kb, Wih, bih, Vb, B * S, H, E, 1);
    // transpose recurrent weights
    transpose512<<<dim3(256), blk, 0, stream>>>(Whh, WT0);
    transpose512<<<dim3(256), blk, 0, stream>>>(Whh + 512 * 512, WT1);
    // layer-0 recurrence; H0[t] stored into Kb slab (overwrites atten_out, already consumed)
    for (int t = 0; t < S; ++t) {
        rnn_step<<<dim3(256), dim3(64), 0, stream>>>(
            Vb + (size_t)t * B * H,
            t ? Kb + (size_t)(t - 1) * B * H : Kb,
            Kb + (size_t)t * B * H, WT0, bhh, t == 0);
    }
    // RNN layer-1 input preactivations: pre1 = H0 @ Wih1^T + bih1 -> Qb (rows already s*B+b)
    gemm_bias<<<g_gemm, blk, 0, stream>>>(Kb, Wih + 512 * 512, bih + 512, Qb, B * S, H, H, 0);
    // layer-1 recurrence with small ping-pong buffers
    for (int t = 0; t < S; ++t) {
        const float* hp = (t & 1) ? h1a : h1b;
        float* ho = (t & 1) ? h1b : h1a;
        rnn_step<<<dim3(256), dim3(64), 0, stream>>>(
            Qb + (size_t)t * B * H, hp, ho, WT1, bhh + 512, t == 0);
    }
    // final FC (last step wrote h1b since 511 is odd)
    fc_out<<<dim3(32), dim3(64), 0, stream>>>(h1b, Wfc, bfc, out);
}

// Round 2
// 8830.417 us; speedup vs baseline: 1.6332x; 1.6332x over previous
//
#include <hip/hip_runtime.h>
#include <hip/hip_bf16.h>

#define B 32
#define S 512
#define E 512
#define H 512
#define NH 8
#define HD 64
#define QT 16

// ---------------- GEMM: C[M,N] = A[M,K] @ W[N,K]^T + bias[N] ----------------
// BM=BN=64, BK=16, 256 threads, 4x4 microtile. Requires M%64==0, N%64==0, K%16==0.
// mode 0: C[r*N+c].  mode 1: scatter rows r=b*S+s -> C[(s*B+b)*N+c] (RNN time-major).
__global__ __launch_bounds__(256) void gemm_bias(const float* __restrict__ A,
                                                 const float* __restrict__ W,
                                                 const float* __restrict__ bias,
                                                 float* __restrict__ C,
                                                 int M, int N, int K, int mode) {
    __shared__ float As[16][68];
    __shared__ float Ws[16][68];
    int t = threadIdx.x;
    int n0 = blockIdx.x * 64;
    int m0 = blockIdx.y * 64;
    int ty = t >> 4, tx = t & 15;
    int lr = t >> 2;          // 0..63
    int lc = (t & 3) * 4;     // 0,4,8,12
    float acc[4][4] = {};
    for (int k0 = 0; k0 < K; k0 += 16) {
        float4 av = *(const float4*)&A[(size_t)(m0 + lr) * K + k0 + lc];
        float4 wv = *(const float4*)&W[(size_t)(n0 + lr) * K + k0 + lc];
        As[lc + 0][lr] = av.x; As[lc + 1][lr] = av.y; As[lc + 2][lr] = av.z; As[lc + 3][lr] = av.w;
        Ws[lc + 0][lr] = wv.x; Ws[lc + 1][lr] = wv.y; Ws[lc + 2][lr] = wv.z; Ws[lc + 3][lr] = wv.w;
        __syncthreads();
#pragma unroll
        for (int kk = 0; kk < 16; ++kk) {
            float4 a = *(const float4*)&As[kk][ty * 4];
            float4 b = *(const float4*)&Ws[kk][tx * 4];
            float ar[4] = {a.x, a.y, a.z, a.w};
            float br[4] = {b.x, b.y, b.z, b.w};
#pragma unroll
            for (int i = 0; i < 4; ++i)
#pragma unroll
                for (int j = 0; j < 4; ++j) acc[i][j] += ar[i] * br[j];
        }
        __syncthreads();
    }
    int c = n0 + tx * 4;
#pragma unroll
    for (int i = 0; i < 4; ++i) {
        int r = m0 + ty * 4 + i;
        size_t rowbase;
        if (mode == 0) rowbase = (size_t)r * N;
        else { int b_ = r / S, s_ = r % S; rowbase = (size_t)(s_ * B + b_) * N; }
        float4 o;
        o.x = acc[i][0] + bias[c + 0];
        o.y = acc[i][1] + bias[c + 1];
        o.z = acc[i][2] + bias[c + 2];
        o.w = acc[i][3] + bias[c + 3];
        *(float4*)&C[rowbase + c] = o;
    }
}

// ---------------- Attention: per (b, h, 16-row q-tile). ctx overwrites Q in place. ----
__global__ __launch_bounds__(256) void attn_kernel(float* __restrict__ Q,
                                                   const float* __restrict__ K,
                                                   const float* __restrict__ V) {
    __shared__ float QsT[64][QT + 1];   // [d][q]
    __shared__ float KVs[64][65];       // [k][d] staging for K then V tiles
    __shared__ float sc[512][QT];       // [k][q] scores
    __shared__ float red[16][QT];
    __shared__ float mx[QT], sminv[QT];
    int t = threadIdx.x;
    int bid = blockIdx.x;
    int qt = bid & 31;            // 32 q-tiles of 16
    int h = (bid >> 5) & 7;
    int b = bid >> 8;
    const int qbase = b * S + qt * QT;
    const int col0 = h * HD;
    // stage Q^T
#pragma unroll
    for (int i = 0; i < 4; ++i) {
        int e = t + i * 256;
        int q = e >> 6, d = e & 63;
        QsT[d][q] = Q[(size_t)(qbase + q) * E + col0 + d];
    }
    int q = t & (QT - 1);
    int g = t >> 4;               // 0..15
    float lmax = -1e30f;
    for (int kt = 0; kt < 8; ++kt) {
        __syncthreads();
#pragma unroll
        for (int i = 0; i < 16; ++i) {
            int e = t + i * 256;
            int k = e >> 6, d = e & 63;
            KVs[k][d] = K[(size_t)(b * S + kt * 64 + k) * E + col0 + d];
        }
        __syncthreads();
#pragma unroll
        for (int kk = 0; kk < 4; ++kk) {
            int kl = g * 4 + kk;
            float s = 0.f;
#pragma unroll
            for (int d = 0; d < 64; ++d) s += QsT[d][q] * KVs[kl][d];
            s *= 0.125f;  // 1/sqrt(64)
            sc[kt * 64 + kl][q] = s;
            lmax = fmaxf(lmax, s);
        }
    }
    red[g][q] = lmax;
    __syncthreads();
    if (t < QT) {
        float m = red[0][t];
#pragma unroll
        for (int i = 1; i < 16; ++i) m = fmaxf(m, red[i][t]);
        mx[t] = m;
    }
    __syncthreads();
    float m = mx[q];
    float lsum = 0.f;
#pragma unroll
    for (int i = 0; i < 32; ++i) {
        int k = g * 32 + i;
        float e = __expf(sc[k][q] - m);
        sc[k][q] = e;
        lsum += e;
    }
    red[g][q] = lsum;
    __syncthreads();
    if (t < QT) {
        float s2 = 0.f;
#pragma unroll
        for (int i = 0; i < 16; ++i) s2 += red[i][t];
        sminv[t] = 1.0f / s2;
    }
    // PV
    float ctx[4] = {0.f, 0.f, 0.f, 0.f};
    int dp = g;
    for (int kt = 0; kt < 8; ++kt) {
        __syncthreads();
#pragma unroll
        for (int i = 0; i < 16; ++i) {
            int e = t + i * 256;
            int k = e >> 6, d = e & 63;
            KVs[k][d] = V[(size_t)(b * S + kt * 64 + k) * E + col0 + d];
        }
        __syncthreads();
        for (int kk = 0; kk < 64; ++kk) {
            float p = sc[kt * 64 + kk][q];
#pragma unroll
            for (int jj = 0; jj < 4; ++jj) ctx[jj] += p * KVs[kk][dp * 4 + jj];
        }
    }
    float inv = sminv[q];
    float4 o;
    o.x = ctx[0] * inv; o.y = ctx[1] * inv; o.z = ctx[2] * inv; o.w = ctx[3] * inv;
    *(float4*)&Q[(size_t)(qbase + q) * E + col0 + dp * 4] = o;
}

// ---------------- zero the sync counters (each call, for graph-replay determinism) ----
__global__ __launch_bounds__(256) void zero_ints(int* __restrict__ p, int n) {
    int i = blockIdx.x * 256 + threadIdx.x;
    if (i < n) p[i] = 0;
}

// ---------------- persistent RNN layer ----------------
// Grid: 256 blocks = 8 j-slices x 32 batch. blockIdx = slice*32 + b.
// Each block owns h[b, slice*64 .. slice*64+63] for all 512 time steps.
// Whh slice lives in VGPRs: thread (kg,jq) holds w[jj=0..3][kk=0..31] =
// Whh[slice*64 + jq*4 + jj][kg*32 + kk].  All cross-block h traffic goes
// through agent-scope atomics (correct across non-coherent XCD L2s).
__global__ __launch_bounds__(256, 2) void rnn_persistent(const float* __restrict__ pre,
                                                         const float* __restrict__ Whh,
                                                         const float* __restrict__ bhh,
                                                         float* __restrict__ hist,
                                                         int* __restrict__ cnt) {
    __shared__ float hl[512];
    __shared__ float part[64][17];
    const int tid = threadIdx.x;
    const int b = blockIdx.x & 31;
    const int sl = blockIdx.x >> 5;
    const int jq = tid & 15;    // 0..15 -> 4 j each
    const int kg = tid >> 4;    // 0..15 -> 32 k each
    const int jbase = sl * 64;
    const int k0 = kg * 32;

    // stage this thread's weight tile into registers (one-time)
    float w0[32], w1[32], w2[32], w3[32];
    {
        const float* r0 = Whh + (size_t)(jbase + jq * 4 + 0) * 512 + k0;
        const float* r1 = Whh + (size_t)(jbase + jq * 4 + 1) * 512 + k0;
        const float* r2 = Whh + (size_t)(jbase + jq * 4 + 2) * 512 + k0;
        const float* r3 = Whh + (size_t)(jbase + jq * 4 + 3) * 512 + k0;
#pragma unroll
        for (int k4 = 0; k4 < 8; ++k4) {
            float4 v0 = *(const float4*)&r0[k4 * 4];
            float4 v1 = *(const float4*)&r1[k4 * 4];
            float4 v2 = *(const float4*)&r2[k4 * 4];
            float4 v3 = *(const float4*)&r3[k4 * 4];
            w0[k4*4+0]=v0.x; w0[k4*4+1]=v0.y; w0[k4*4+2]=v0.z; w0[k4*4+3]=v0.w;
            w1[k4*4+0]=v1.x; w1[k4*4+1]=v1.y; w1[k4*4+2]=v1.z; w1[k4*4+3]=v1.w;
            w2[k4*4+0]=v2.x; w2[k4*4+1]=v2.y; w2[k4*4+2]=v2.z; w2[k4*4+3]=v2.w;
            w3[k4*4+0]=v3.x; w3[k4*4+1]=v3.y; w3[k4*4+2]=v3.z; w3[k4*4+3]=v3.w;
        }
    }
    const float bj = bhh[jbase + (tid & 63)];

    for (int t = 0; t < S; ++t) {
        float a0 = 0.f, a1 = 0.f, a2 = 0.f, a3 = 0.f;
        if (t > 0) {
            if (tid == 0) {
                while (__hip_atomic_load(&cnt[b * S + (t - 1)], __ATOMIC_ACQUIRE,
                                         __HIP_MEMORY_SCOPE_AGENT) < 8) {
                    __builtin_amdgcn_s_sleep(2);
                }
            }
            __syncthreads();
            const float* hsrc = hist + (size_t)(t - 1) * (B * H) + b * H;
            float v0 = __hip_atomic_load(&hsrc[tid * 2 + 0], __ATOMIC_RELAXED,
                                         __HIP_MEMORY_SCOPE_AGENT);
            float v1 = __hip_atomic_load(&hsrc[tid * 2 + 1], __ATOMIC_RELAXED,
                                         __HIP_MEMORY_SCOPE_AGENT);
            hl[tid * 2 + 0] = v0;
            hl[tid * 2 + 1] = v1;
            __syncthreads();
#pragma unroll
            for (int k4 = 0; k4 < 8; ++k4) {
                float4 hv = *(const float4*)&hl[k0 + k4 * 4];
                a0 += w0[k4*4+0]*hv.x + w0[k4*4+1]*hv.y + w0[k4*4+2]*hv.z + w0[k4*4+3]*hv.w;
                a1 += w1[k4*4+0]*hv.x + w1[k4*4+1]*hv.y + w1[k4*4+2]*hv.z + w1[k4*4+3]*hv.w;
                a2 += w2[k4*4+0]*hv.x + w2[k4*4+1]*hv.y + w2[k4*4+2]*hv.z + w2[k4*4+3]*hv.w;
                a3 += w3[k4*4+0]*hv.x + w3[k4*4+1]*hv.y + w3[k4*4+2]*hv.z + w3[k4*4+3]*hv.w;
            }
            __syncthreads();  // protect hl before next-step overwrite; also orders part reuse
        }
        part[jq * 4 + 0][kg] = a0;
        part[jq * 4 + 1][kg] = a1;
        part[jq * 4 + 2][kg] = a2;
        part[jq * 4 + 3][kg] = a3;
        __syncthreads();
        if (tid < 64) {
            float s = 0.f;
#pragma unroll
            for (int i = 0; i < 16; ++i) s += part[tid][i];
            s += pre[(size_t)t * (B * H) + b * H + jbase + tid] + bj;
            float ex = __expf(2.f * s);
            float hval = (ex - 1.f) / (ex + 1.f);
            __hip_atomic_store(&hist[(size_t)t * (B * H) + b * H + jbase + tid], hval,
                               __ATOMIC_RELAXED, __HIP_MEMORY_SCOPE_AGENT);
        }
        __syncthreads();  // all stores retired (vmcnt) before the signal
        if (tid == 0) {
            __hip_atomic_fetch_add(&cnt[b * S + t], 1, __ATOMIC_RELEASE,
                                   __HIP_MEMORY_SCOPE_AGENT);
        }
    }
}

// ---------------- final FC: out[b] = h[b,:] . Wfc[0,:] + bfc[0] ----------------
__global__ __launch_bounds__(64) void fc_out(const float* __restrict__ h,
                                             const float* __restrict__ Wfc,
                                             const float* __restrict__ bfc,
                                             float* __restrict__ out) {
    int b = blockIdx.x;
    int t = threadIdx.x;
    float a = 0.f;
    for (int j = t; j < 512; j += 64) a += h[b * 512 + j] * Wfc[j];
#pragma unroll
    for (int o = 32; o; o >>= 1) a += __shfl_down(a, o, 64);
    if (t == 0) out[b] = a + bfc[0];
}

extern "C" void kernel_launch(void* const* d_in, const int* in_sizes, int n_in,
                              void* d_out, int out_size, void* d_ws, size_t ws_size,
                              hipStream_t stream) {
    const float* x   = (const float*)d_in[0];
    const float* Wq  = (const float*)d_in[1];
    const float* bq  = (const float*)d_in[2];
    const float* Wk  = (const float*)d_in[3];
    const float* bk  = (const float*)d_in[4];
    const float* Wv  = (const float*)d_in[5];
    const float* bv  = (const float*)d_in[6];
    const float* Wo  = (const float*)d_in[7];
    const float* bo  = (const float*)d_in[8];
    const float* Wih = (const float*)d_in[9];
    const float* bih = (const float*)d_in[10];
    const float* Whh = (const float*)d_in[11];
    const float* bhh = (const float*)d_in[12];
    const float* Wfc = (const float*)d_in[13];
    const float* bfc = (const float*)d_in[14];
    float* out = (float*)d_out;
    float* ws = (float*)d_ws;

    float* Qb  = ws;                                  // 8M floats: Q -> ctx -> pre1
    float* Kb  = ws + (size_t)8 * 1024 * 1024;        // 8M: K -> atten_out -> hist0
    float* Vb  = ws + (size_t)16 * 1024 * 1024;       // 8M: V -> pre0 -> hist1
    int*   cnt = (int*)(ws + (size_t)24 * 1024 * 1024); // 2*B*S ints

    dim3 blk(256);
    dim3 g_gemm(E / 64, (B * S) / 64);

    // zero sync counters (must happen every call: graph replays reuse the buffer)
    zero_ints<<<dim3((2 * B * S + 255) / 256), blk, 0, stream>>>(cnt, 2 * B * S);

    // QKV projections
    gemm_bias<<<g_gemm, blk, 0, stream>>>(x, Wq, bq, Qb, B * S, E, E, 0);
    gemm_bias<<<g_gemm, blk, 0, stream>>>(x, Wk, bk, Kb, B * S, E, E, 0);
    gemm_bias<<<g_gemm, blk, 0, stream>>>(x, Wv, bv, Vb, B * S, E, E, 0);
    // attention (ctx -> Qb in place)
    attn_kernel<<<dim3(B * NH * (S / QT)), blk, 0, stream>>>(Qb, Kb, Vb);
    // output projection: atten_out -> Kb
    gemm_bias<<<g_gemm, blk, 0, stream>>>(Qb, Wo, bo, Kb, B * S, E, E, 0);
    // RNN layer-0 input preactivations, time-major: pre0 -> Vb
    gemm_bias<<<g_gemm, blk, 0, stream>>>(Kb, Wih, bih, Vb, B * S, H, E, 1);
    // layer-0 recurrence (persistent): hist0 -> Kb (atten_out already consumed)
    rnn_persistent<<<dim3(256), blk, 0, stream>>>(Vb, Whh, bhh, Kb, cnt);
    // RNN layer-1 input preactivations: pre1 = hist0 @ Wih1^T + bih1 -> Qb
    gemm_bias<<<g_gemm, blk, 0, stream>>>(Kb, Wih + 512 * 512, bih + 512, Qb, B * S, H, H, 0);
    // layer-1 recurrence (persistent): hist1 -> Vb (pre0 already consumed)
    rnn_persistent<<<dim3(256), blk, 0, stream>>>(Qb, Whh + 512 * 512, bhh + 512, Vb,
                                                  cnt + B * S);
    // final FC on last hidden state hist1[511]
    fc_out<<<dim3(32), dim3(64), 0, stream>>>(Vb + (size_t)511 * B * H, Wfc, bfc, out);
}

// Round 3
// 6639.529 us; speedup vs baseline: 2.1721x; 1.3300x over previous
//
#include <hip/hip_runtime.h>
#include <hip/hip_fp16.h>

#define B 32
#define S 512
#define E 512
#define H 512
#define NH 8
#define HD 64

typedef _Float16 h16x8 __attribute__((ext_vector_type(8)));
typedef _Float16 h16x4 __attribute__((ext_vector_type(4)));
typedef float f32x4 __attribute__((ext_vector_type(4)));

// ---------------- fp32 -> fp16 cast (vectorized, grid-stride) ----------------
__global__ __launch_bounds__(256) void cast_h(const float* __restrict__ src,
                                              _Float16* __restrict__ dst, int n4) {
    int i = blockIdx.x * 256 + threadIdx.x;
    const int stride = gridDim.x * 256;
    for (; i < n4; i += stride) {
        float4 v = ((const float4*)src)[i];
        h16x4 o;
        o[0] = (_Float16)v.x; o[1] = (_Float16)v.y;
        o[2] = (_Float16)v.z; o[3] = (_Float16)v.w;
        ((h16x4*)dst)[i] = o;
    }
}

// ---------------- MFMA GEMM: C[M,N] = A[M,K] @ W[N,K]^T + bias ----------------
// A,W fp16 row-major. 128x128 tile, BK=32, 256 thr (4 waves, 2x2), 4x4 16x16 frags.
// OMODE 0: f32 row-major. 1: f16 row-major. 2: f16 scattered to Vt[(b*8+h)*64+d][s].
// 3: f32 time-major scatter row r=b*512+s -> C[(s*32+b)*N+c].
template <int OMODE>
__global__ __launch_bounds__(256) void gemm_mfma(const _Float16* __restrict__ A,
                                                 const _Float16* __restrict__ W,
                                                 const float* __restrict__ bias,
                                                 void* __restrict__ Cout,
                                                 int M, int N, int K) {
    __shared__ __align__(16) _Float16 Als[128 * 32];
    __shared__ __align__(16) _Float16 Bls[128 * 32];
    const int tid = threadIdx.x;
    const int m0 = blockIdx.y * 128;
    const int n0 = blockIdx.x * 128;
    const int lane = tid & 63;
    const int w = tid >> 6;
    const int wm = w >> 1, wn = w & 1;
    f32x4 acc[4][4] = {};

    const int srow = tid >> 1;       // 0..127
    const int shalf = tid & 1;       // 32B half of the 64B row
    const _Float16* Ag = A + (size_t)(m0 + srow) * K + shalf * 16;
    const _Float16* Wg = W + (size_t)(n0 + srow) * K + shalf * 16;

    for (int k0 = 0; k0 < K; k0 += 32) {
        h16x8 a0 = *(const h16x8*)(Ag + k0);
        h16x8 a1 = *(const h16x8*)(Ag + k0 + 8);
        h16x8 b0 = *(const h16x8*)(Wg + k0);
        h16x8 b1 = *(const h16x8*)(Wg + k0 + 8);
        __syncthreads();   // previous iter's LDS reads complete
        *(h16x8*)&Als[srow * 32 + shalf * 16] = a0;
        *(h16x8*)&Als[srow * 32 + shalf * 16 + 8] = a1;
        *(h16x8*)&Bls[srow * 32 + shalf * 16] = b0;
        *(h16x8*)&Bls[srow * 32 + shalf * 16 + 8] = b1;
        __syncthreads();
        h16x8 af[4], bf[4];
#pragma unroll
        for (int mt = 0; mt < 4; ++mt)
            af[mt] = *(const h16x8*)&Als[(wm * 64 + mt * 16 + (lane & 15)) * 32 + (lane >> 4) * 8];
#pragma unroll
        for (int nt = 0; nt < 4; ++nt)
            bf[nt] = *(const h16x8*)&Bls[(wn * 64 + nt * 16 + (lane & 15)) * 32 + (lane >> 4) * 8];
#pragma unroll
        for (int mt = 0; mt < 4; ++mt)
#pragma unroll
            for (int nt = 0; nt < 4; ++nt)
                acc[mt][nt] = __builtin_amdgcn_mfma_f32_16x16x32_f16(af[mt], bf[nt], acc[mt][nt], 0, 0, 0);
    }

    float* Cf = (float*)Cout;
    _Float16* Ch = (_Float16*)Cout;
    const int colb = n0 + wn * 64 + (lane & 15);
    const int rowb = m0 + wm * 64 + ((lane >> 4) << 2);
#pragma unroll
    for (int mt = 0; mt < 4; ++mt) {
#pragma unroll
        for (int nt = 0; nt < 4; ++nt) {
            const int c = colb + nt * 16;
            const float bv = bias[c];
            if (OMODE == 2) {
                const int R0 = rowb + mt * 16;
                const int bb = R0 >> 9, s = R0 & 511, hh = c >> 6, d = c & 63;
                h16x4 pk;
#pragma unroll
                for (int j = 0; j < 4; ++j) pk[j] = (_Float16)(acc[mt][nt][j] + bv);
                *(h16x4*)&Ch[((size_t)(bb * 8 + hh) * 64 + d) * 512 + s] = pk;
            } else {
#pragma unroll
                for (int j = 0; j < 4; ++j) {
                    const int R = rowb + mt * 16 + j;
                    const float v = acc[mt][nt][j] + bv;
                    if (OMODE == 0) Cf[(size_t)R * N + c] = v;
                    else if (OMODE == 3) Cf[((size_t)(R & 511) * 32 + (R >> 9)) * N + c] = v;
                    else Ch[(size_t)R * N + c] = (_Float16)v;
                }
            }
        }
    }
}

// ---------------- MFMA flash attention: per (b, h, 64-row q-tile) ----------------
// Qb/Kb f16 [16384][512]; Vt f16 [(b*8+h)*64+d][512 s]. ctx overwrites Qb in place.
__global__ __launch_bounds__(256) void attn_mfma(_Float16* __restrict__ Qb,
                                                 const _Float16* __restrict__ Kb,
                                                 const _Float16* __restrict__ Vt) {
    __shared__ __align__(16) _Float16 Qs[64 * 72];
    __shared__ __align__(16) _Float16 Ks[64 * 72];
    __shared__ __align__(16) _Float16 Vs[64 * 72];
    __shared__ __align__(16) _Float16 Ps[4 * 16 * 72];
    const int tid = threadIdx.x;
    const int lane = tid & 63;
    const int w = tid >> 6;
    const int qt = blockIdx.x & 7;
    const int h = (blockIdx.x >> 3) & 7;
    const int b = blockIdx.x >> 6;
    const size_t qrow0 = (size_t)b * 512 + qt * 64;
    const int col0 = h * 64;

    {   // stage Q tile [64 q][64 d]
        const int r = tid >> 2;
        const int c0 = (tid & 3) << 4;
        const _Float16* gq = &Qb[(qrow0 + r) * 512 + col0 + c0];
        *(h16x8*)&Qs[r * 72 + c0] = *(const h16x8*)(gq);
        *(h16x8*)&Qs[r * 72 + c0 + 8] = *(const h16x8*)(gq + 8);
    }
    __syncthreads();
    h16x8 aq[2];
#pragma unroll
    for (int ks = 0; ks < 2; ++ks)
        aq[ks] = *(const h16x8*)&Qs[(w * 16 + (lane & 15)) * 72 + ks * 32 + (lane >> 4) * 8];

    float m[4] = {-1e30f, -1e30f, -1e30f, -1e30f};
    float l[4] = {0.f, 0.f, 0.f, 0.f};
    f32x4 acco[4] = {};

    for (int kt = 0; kt < 8; ++kt) {
        __syncthreads();   // previous PV reads done before restage
        {
            const int r = tid >> 2;
            const int c0 = (tid & 3) << 4;
            const _Float16* gk = &Kb[((size_t)b * 512 + kt * 64 + r) * 512 + col0 + c0];
            *(h16x8*)&Ks[r * 72 + c0] = *(const h16x8*)(gk);
            *(h16x8*)&Ks[r * 72 + c0 + 8] = *(const h16x8*)(gk + 8);
            const _Float16* gv = &Vt[((size_t)(b * 8 + h) * 64 + r) * 512 + kt * 64 + c0];
            *(h16x8*)&Vs[r * 72 + c0] = *(const h16x8*)(gv);
            *(h16x8*)&Vs[r * 72 + c0 + 8] = *(const h16x8*)(gv + 8);
        }
        __syncthreads();
        // S = Q @ K^T  (rows q, cols kv)
        f32x4 accs[4] = {};
#pragma unroll
        for (int nt = 0; nt < 4; ++nt) {
#pragma unroll
            for (int ks = 0; ks < 2; ++ks) {
                h16x8 bk = *(const h16x8*)&Ks[(nt * 16 + (lane & 15)) * 72 + ks * 32 + (lane >> 4) * 8];
                accs[nt] = __builtin_amdgcn_mfma_f32_16x16x32_f16(aq[ks], bk, accs[nt], 0, 0, 0);
            }
        }
        // online softmax (scale 0.125 folded into exp args)
#pragma unroll
        for (int j = 0; j < 4; ++j) {
            float v = fmaxf(fmaxf(accs[0][j], accs[1][j]), fmaxf(accs[2][j], accs[3][j]));
#pragma unroll
            for (int o = 1; o < 16; o <<= 1) v = fmaxf(v, __shfl_xor(v, o, 64));
            const float mn = fmaxf(m[j], v);
            const float scl = __expf(0.125f * (m[j] - mn));
            m[j] = mn;
            l[j] *= scl;
#pragma unroll
            for (int nt2 = 0; nt2 < 4; ++nt2) acco[nt2][j] *= scl;
            float ps = 0.f;
            const int prow = ((lane >> 4) << 2) + j;
#pragma unroll
            for (int nt = 0; nt < 4; ++nt) {
                const float p = __expf(0.125f * (accs[nt][j] - mn));
                ps += p;
                Ps[w * 16 * 72 + prow * 72 + nt * 16 + (lane & 15)] = (_Float16)p;
            }
#pragma unroll
            for (int o = 1; o < 16; o <<= 1) ps += __shfl_xor(ps, o, 64);
            l[j] += ps;
        }
        __syncthreads();   // Ps visible, Ks reads done
        // ctx += P @ V
#pragma unroll
        for (int ks2 = 0; ks2 < 2; ++ks2) {
            h16x8 pa = *(const h16x8*)&Ps[w * 16 * 72 + (lane & 15) * 72 + ks2 * 32 + (lane >> 4) * 8];
#pragma unroll
            for (int nt2 = 0; nt2 < 4; ++nt2) {
                h16x8 bv = *(const h16x8*)&Vs[(nt2 * 16 + (lane & 15)) * 72 + ks2 * 32 + (lane >> 4) * 8];
                acco[nt2] = __builtin_amdgcn_mfma_f32_16x16x32_f16(pa, bv, acco[nt2], 0, 0, 0);
            }
        }
    }
    // epilogue: normalize, write ctx in place (f16)
#pragma unroll
    for (int j = 0; j < 4; ++j) {
        const float inv = 1.0f / l[j];
        const size_t r = qrow0 + w * 16 + ((lane >> 4) << 2) + j;
#pragma unroll
        for (int nt2 = 0; nt2 < 4; ++nt2)
            Qb[r * 512 + col0 + nt2 * 16 + (lane & 15)] = (_Float16)(acco[nt2][j] * inv);
    }
}

// ---------------- zero the sync counters ----------------
__global__ __launch_bounds__(256) void zero_ints(int* __restrict__ p, int n) {
    int i = blockIdx.x * 256 + threadIdx.x;
    if (i < n) p[i] = 0;
}

// ---------------- persistent RNN layer (fp32; also emits f16 copy of h) ----------------
__global__ __launch_bounds__(256, 2) void rnn_persistent(const float* __restrict__ pre,
                                                         const float* __restrict__ Whh,
                                                         const float* __restrict__ bhh,
                                                         float* __restrict__ hist,
                                                         _Float16* __restrict__ hist_h,
                                                         int* __restrict__ cnt) {
    __shared__ float hl[512];
    __shared__ float part[64][17];
    const int tid = threadIdx.x;
    const int b = blockIdx.x & 31;
    const int sl = blockIdx.x >> 5;
    const int jq = tid & 15;
    const int kg = tid >> 4;
    const int jbase = sl * 64;
    const int k0 = kg * 32;

    float w0[32], w1[32], w2[32], w3[32];
    {
        const float* r0 = Whh + (size_t)(jbase + jq * 4 + 0) * 512 + k0;
        const float* r1 = Whh + (size_t)(jbase + jq * 4 + 1) * 512 + k0;
        const float* r2 = Whh + (size_t)(jbase + jq * 4 + 2) * 512 + k0;
        const float* r3 = Whh + (size_t)(jbase + jq * 4 + 3) * 512 + k0;
#pragma unroll
        for (int k4 = 0; k4 < 8; ++k4) {
            float4 v0 = *(const float4*)&r0[k4 * 4];
            float4 v1 = *(const float4*)&r1[k4 * 4];
            float4 v2 = *(const float4*)&r2[k4 * 4];
            float4 v3 = *(const float4*)&r3[k4 * 4];
            w0[k4*4+0]=v0.x; w0[k4*4+1]=v0.y; w0[k4*4+2]=v0.z; w0[k4*4+3]=v0.w;
            w1[k4*4+0]=v1.x; w1[k4*4+1]=v1.y; w1[k4*4+2]=v1.z; w1[k4*4+3]=v1.w;
            w2[k4*4+0]=v2.x; w2[k4*4+1]=v2.y; w2[k4*4+2]=v2.z; w2[k4*4+3]=v2.w;
            w3[k4*4+0]=v3.x; w3[k4*4+1]=v3.y; w3[k4*4+2]=v3.z; w3[k4*4+3]=v3.w;
        }
    }
    const float bj = bhh[jbase + (tid & 63)];

    for (int t = 0; t < S; ++t) {
        float a0 = 0.f, a1 = 0.f, a2 = 0.f, a3 = 0.f;
        if (t > 0) {
            if (tid == 0) {
                while (__hip_atomic_load(&cnt[b * S + (t - 1)], __ATOMIC_ACQUIRE,
                                         __HIP_MEMORY_SCOPE_AGENT) < 8) {
                    __builtin_amdgcn_s_sleep(2);
                }
            }
            __syncthreads();
            const float* hsrc = hist + (size_t)(t - 1) * (B * H) + b * H;
            float v0 = __hip_atomic_load(&hsrc[tid * 2 + 0], __ATOMIC_RELAXED,
                                         __HIP_MEMORY_SCOPE_AGENT);
            float v1 = __hip_atomic_load(&hsrc[tid * 2 + 1], __ATOMIC_RELAXED,
                                         __HIP_MEMORY_SCOPE_AGENT);
            hl[tid * 2 + 0] = v0;
            hl[tid * 2 + 1] = v1;
            __syncthreads();
#pragma unroll
            for (int k4 = 0; k4 < 8; ++k4) {
                float4 hv = *(const float4*)&hl[k0 + k4 * 4];
                a0 += w0[k4*4+0]*hv.x + w0[k4*4+1]*hv.y + w0[k4*4+2]*hv.z + w0[k4*4+3]*hv.w;
                a1 += w1[k4*4+0]*hv.x + w1[k4*4+1]*hv.y + w1[k4*4+2]*hv.z + w1[k4*4+3]*hv.w;
                a2 += w2[k4*4+0]*hv.x + w2[k4*4+1]*hv.y + w2[k4*4+2]*hv.z + w2[k4*4+3]*hv.w;
                a3 += w3[k4*4+0]*hv.x + w3[k4*4+1]*hv.y + w3[k4*4+2]*hv.z + w3[k4*4+3]*hv.w;
            }
            __syncthreads();
        }
        part[jq * 4 + 0][kg] = a0;
        part[jq * 4 + 1][kg] = a1;
        part[jq * 4 + 2][kg] = a2;
        part[jq * 4 + 3][kg] = a3;
        __syncthreads();
        if (tid < 64) {
            float s = 0.f;
#pragma unroll
            for (int i = 0; i < 16; ++i) s += part[tid][i];
            s += pre[(size_t)t * (B * H) + b * H + jbase + tid] + bj;
            float ex = __expf(2.f * s);
            float hval = (ex - 1.f) / (ex + 1.f);
            const size_t idx = (size_t)t * (B * H) + b * H + jbase + tid;
            __hip_atomic_store(&hist[idx], hval, __ATOMIC_RELAXED, __HIP_MEMORY_SCOPE_AGENT);
            hist_h[idx] = (_Float16)hval;
        }
        __syncthreads();
        if (tid == 0) {
            __hip_atomic_fetch_add(&cnt[b * S + t], 1, __ATOMIC_RELEASE,
                                   __HIP_MEMORY_SCOPE_AGENT);
        }
    }
}

// ---------------- final FC ----------------
__global__ __launch_bounds__(64) void fc_out(const float* __restrict__ h,
                                             const float* __restrict__ Wfc,
                                             const float* __restrict__ bfc,
                                             float* __restrict__ out) {
    int b = blockIdx.x;
    int t = threadIdx.x;
    float a = 0.f;
    for (int j = t; j < 512; j += 64) a += h[b * 512 + j] * Wfc[j];
#pragma unroll
    for (int o = 32; o; o >>= 1) a += __shfl_down(a, o, 64);
    if (t == 0) out[b] = a + bfc[0];
}

extern "C" void kernel_launch(void* const* d_in, const int* in_sizes, int n_in,
                              void* d_out, int out_size, void* d_ws, size_t ws_size,
                              hipStream_t stream) {
    const float* x   = (const float*)d_in[0];
    const float* Wq  = (const float*)d_in[1];
    const float* bq  = (const float*)d_in[2];
    const float* Wk  = (const float*)d_in[3];
    const float* bk  = (const float*)d_in[4];
    const float* Wv  = (const float*)d_in[5];
    const float* bv  = (const float*)d_in[6];
    const float* Wo  = (const float*)d_in[7];
    const float* bo  = (const float*)d_in[8];
    const float* Wih = (const float*)d_in[9];
    const float* bih = (const float*)d_in[10];
    const float* Whh = (const float*)d_in[11];
    const float* bhh = (const float*)d_in[12];
    const float* Wfc = (const float*)d_in[13];
    const float* bfc = (const float*)d_in[14];
    float* out = (float*)d_out;
    char* base = (char*)d_ws;

    // S0 [0,32M): x_f16 (16MB) -> pre0/pre1 f32 (32MB)
    // S1 [32M,48M): Q_f16 -> ctx (in place) -> hist0_f16
    // S2 [48M,64M): K_f16 -> atten_out f16
    // S3 [64M,80M): Vt f16 -> (dummy f16 sink for layer1)
    // S4 [80M,112M): hist f32 (layer0, then layer1)
    // S6 [112M,115M): 6 f16 weights; cnt at 115M
    _Float16* xh   = (_Float16*)(base);
    float*    pre  = (float*)(base);
    _Float16* Qh   = (_Float16*)(base + ((size_t)32 << 20));
    _Float16* Kh   = (_Float16*)(base + ((size_t)48 << 20));
    _Float16* Vth  = (_Float16*)(base + ((size_t)64 << 20));
    float*    hist = (float*)(base + ((size_t)80 << 20));
    _Float16* wgt  = (_Float16*)(base + ((size_t)112 << 20));
    int*      cnt  = (int*)(base + ((size_t)115 << 20));
    const int WSZ = 512 * 512;

    cast_h<<<dim3(4096), dim3(256), 0, stream>>>(x, xh, (B * S * E) / 4);
    cast_h<<<dim3(256), dim3(256), 0, stream>>>(Wq, wgt + 0 * (size_t)WSZ, WSZ / 4);
    cast_h<<<dim3(256), dim3(256), 0, stream>>>(Wk, wgt + 1 * (size_t)WSZ, WSZ / 4);
    cast_h<<<dim3(256), dim3(256), 0, stream>>>(Wv, wgt + 2 * (size_t)WSZ, WSZ / 4);
    cast_h<<<dim3(256), dim3(256), 0, stream>>>(Wo, wgt + 3 * (size_t)WSZ, WSZ / 4);
    cast_h<<<dim3(256), dim3(256), 0, stream>>>(Wih, wgt + 4 * (size_t)WSZ, WSZ / 4);
    cast_h<<<dim3(256), dim3(256), 0, stream>>>(Wih + WSZ, wgt + 5 * (size_t)WSZ, WSZ / 4);
    zero_ints<<<dim3((2 * B * S + 255) / 256), dim3(256), 0, stream>>>(cnt, 2 * B * S);

    const dim3 gg(4, 128), blk(256);
    gemm_mfma<1><<<gg, blk, 0, stream>>>(xh, wgt + 0 * (size_t)WSZ, bq, Qh, B * S, E, E);
    gemm_mfma<1><<<gg, blk, 0, stream>>>(xh, wgt + 1 * (size_t)WSZ, bk, Kh, B * S, E, E);
    gemm_mfma<2><<<gg, blk, 0, stream>>>(xh, wgt + 2 * (size_t)WSZ, bv, Vth, B * S, E, E);
    attn_mfma<<<dim3(B * NH * 8), blk, 0, stream>>>(Qh, Kh, Vth);
    gemm_mfma<1><<<gg, blk, 0, stream>>>(Qh, wgt + 3 * (size_t)WSZ, bo, Kh, B * S, E, E);
    gemm_mfma<3><<<gg, blk, 0, stream>>>(Kh, wgt + 4 * (size_t)WSZ, bih, pre, B * S, H, E);
    rnn_persistent<<<dim3(256), blk, 0, stream>>>(pre, Whh, bhh, hist, Qh, cnt);
    gemm_mfma<0><<<gg, blk, 0, stream>>>(Qh, wgt + 5 * (size_t)WSZ, bih + 512, pre, B * S, H, H);
    rnn_persistent<<<dim3(256), blk, 0, stream>>>(pre, Whh + WSZ, bhh + 512, hist, Vth,
                                                  cnt + B * S);
    fc_out<<<dim3(32), dim3(64), 0, stream>>>(hist + (size_t)511 * B * H, Wfc, bfc, out);
}

// Round 7
// 1407.827 us; speedup vs baseline: 10.2438x; 4.7162x over previous
//
#include <hip/hip_runtime.h>
#include <hip/hip_fp16.h>

#define B 32
#define S 512
#define E 512
#define H 512
#define NH 8
#define HD 64
#define POISON 0x7FC0DEADu

typedef _Float16 h16x8 __attribute__((ext_vector_type(8)));
typedef _Float16 h16x4 __attribute__((ext_vector_type(4)));
typedef float f32x4 __attribute__((ext_vector_type(4)));

// ---------------- fp32 -> fp16 cast (vectorized, grid-stride) ----------------
__global__ __launch_bounds__(256) void cast_h(const float* __restrict__ src,
                                              _Float16* __restrict__ dst, int n4) {
    int i = blockIdx.x * 256 + threadIdx.x;
    const int stride = gridDim.x * 256;
    for (; i < n4; i += stride) {
        float4 v = ((const float4*)src)[i];
        h16x4 o;
        o[0] = (_Float16)v.x; o[1] = (_Float16)v.y;
        o[2] = (_Float16)v.z; o[3] = (_Float16)v.w;
        ((h16x4*)dst)[i] = o;
    }
}

// ---------------- MFMA GEMM: C[M,N] = A[M,K] @ W[N,K]^T + bias ----------------
// OMODE 0: f32 row-major. 1: f16 row-major. 2: f16 scattered to Vt[(b*8+h)*64+d][s].
// 3: f32 time-major scatter row r=b*512+s -> C[(s*32+b)*N+c].
template <int OMODE>
__global__ __launch_bounds__(256) void gemm_mfma(const _Float16* __restrict__ A,
                                                 const _Float16* __restrict__ W,
                                                 const float* __restrict__ bias,
                                                 void* __restrict__ Cout,
                                                 int M, int N, int K) {
    __shared__ __align__(16) _Float16 Als[128 * 32];
    __shared__ __align__(16) _Float16 Bls[128 * 32];
    const int tid = threadIdx.x;
    const int m0 = blockIdx.y * 128;
    const int n0 = blockIdx.x * 128;
    const int lane = tid & 63;
    const int w = tid >> 6;
    const int wm = w >> 1, wn = w & 1;
    f32x4 acc[4][4] = {};

    const int srow = tid >> 1;
    const int shalf = tid & 1;
    const _Float16* Ag = A + (size_t)(m0 + srow) * K + shalf * 16;
    const _Float16* Wg = W + (size_t)(n0 + srow) * K + shalf * 16;

    for (int k0 = 0; k0 < K; k0 += 32) {
        h16x8 a0 = *(const h16x8*)(Ag + k0);
        h16x8 a1 = *(const h16x8*)(Ag + k0 + 8);
        h16x8 b0 = *(const h16x8*)(Wg + k0);
        h16x8 b1 = *(const h16x8*)(Wg + k0 + 8);
        __syncthreads();
        *(h16x8*)&Als[srow * 32 + shalf * 16] = a0;
        *(h16x8*)&Als[srow * 32 + shalf * 16 + 8] = a1;
        *(h16x8*)&Bls[srow * 32 + shalf * 16] = b0;
        *(h16x8*)&Bls[srow * 32 + shalf * 16 + 8] = b1;
        __syncthreads();
        h16x8 af[4], bf[4];
#pragma unroll
        for (int mt = 0; mt < 4; ++mt)
            af[mt] = *(const h16x8*)&Als[(wm * 64 + mt * 16 + (lane & 15)) * 32 + (lane >> 4) * 8];
#pragma unroll
        for (int nt = 0; nt < 4; ++nt)
            bf[nt] = *(const h16x8*)&Bls[(wn * 64 + nt * 16 + (lane & 15)) * 32 + (lane >> 4) * 8];
#pragma unroll
        for (int mt = 0; mt < 4; ++mt)
#pragma unroll
            for (int nt = 0; nt < 4; ++nt)
                acc[mt][nt] = __builtin_amdgcn_mfma_f32_16x16x32_f16(af[mt], bf[nt], acc[mt][nt], 0, 0, 0);
    }

    float* Cf = (float*)Cout;
    _Float16* Ch = (_Float16*)Cout;
    const int colb = n0 + wn * 64 + (lane & 15);
    const int rowb = m0 + wm * 64 + ((lane >> 4) << 2);
#pragma unroll
    for (int mt = 0; mt < 4; ++mt) {
#pragma unroll
        for (int nt = 0; nt < 4; ++nt) {
            const int c = colb + nt * 16;
            const float bv = bias[c];
            if (OMODE == 2) {
                const int R0 = rowb + mt * 16;
                const int bb = R0 >> 9, s = R0 & 511, hh = c >> 6, d = c & 63;
                h16x4 pk;
#pragma unroll
                for (int j = 0; j < 4; ++j) pk[j] = (_Float16)(acc[mt][nt][j] + bv);
                *(h16x4*)&Ch[((size_t)(bb * 8 + hh) * 64 + d) * 512 + s] = pk;
            } else {
#pragma unroll
                for (int j = 0; j < 4; ++j) {
                    const int R = rowb + mt * 16 + j;
                    const float v = acc[mt][nt][j] + bv;
                    if (OMODE == 0) Cf[(size_t)R * N + c] = v;
                    else if (OMODE == 3) Cf[((size_t)(R & 511) * 32 + (R >> 9)) * N + c] = v;
                    else Ch[(size_t)R * N + c] = (_Float16)v;
                }
            }
        }
    }
}

// ---------------- MFMA flash attention: per (b, h, 64-row q-tile) ----------------
__global__ __launch_bounds__(256) void attn_mfma(_Float16* __restrict__ Qb,
                                                 const _Float16* __restrict__ Kb,
                                                 const _Float16* __restrict__ Vt) {
    __shared__ __align__(16) _Float16 Qs[64 * 72];
    __shared__ __align__(16) _Float16 Ks[64 * 72];
    __shared__ __align__(16) _Float16 Vs[64 * 72];
    __shared__ __align__(16) _Float16 Ps[4 * 16 * 72];
    const int tid = threadIdx.x;
    const int lane = tid & 63;
    const int w = tid >> 6;
    const int qt = blockIdx.x & 7;
    const int h = (blockIdx.x >> 3) & 7;
    const int b = blockIdx.x >> 6;
    const size_t qrow0 = (size_t)b * 512 + qt * 64;
    const int col0 = h * 64;

    {
        const int r = tid >> 2;
        const int c0 = (tid & 3) << 4;
        const _Float16* gq = &Qb[(qrow0 + r) * 512 + col0 + c0];
        *(h16x8*)&Qs[r * 72 + c0] = *(const h16x8*)(gq);
        *(h16x8*)&Qs[r * 72 + c0 + 8] = *(const h16x8*)(gq + 8);
    }
    __syncthreads();
    h16x8 aq[2];
#pragma unroll
    for (int ks = 0; ks < 2; ++ks)
        aq[ks] = *(const h16x8*)&Qs[(w * 16 + (lane & 15)) * 72 + ks * 32 + (lane >> 4) * 8];

    float m[4] = {-1e30f, -1e30f, -1e30f, -1e30f};
    float l[4] = {0.f, 0.f, 0.f, 0.f};
    f32x4 acco[4] = {};

    for (int kt = 0; kt < 8; ++kt) {
        __syncthreads();
        {
            const int r = tid >> 2;
            const int c0 = (tid & 3) << 4;
            const _Float16* gk = &Kb[((size_t)b * 512 + kt * 64 + r) * 512 + col0 + c0];
            *(h16x8*)&Ks[r * 72 + c0] = *(const h16x8*)(gk);
            *(h16x8*)&Ks[r * 72 + c0 + 8] = *(const h16x8*)(gk + 8);
            const _Float16* gv = &Vt[((size_t)(b * 8 + h) * 64 + r) * 512 + kt * 64 + c0];
            *(h16x8*)&Vs[r * 72 + c0] = *(const h16x8*)(gv);
            *(h16x8*)&Vs[r * 72 + c0 + 8] = *(const h16x8*)(gv + 8);
        }
        __syncthreads();
        f32x4 accs[4] = {};
#pragma unroll
        for (int nt = 0; nt < 4; ++nt) {
#pragma unroll
            for (int ks = 0; ks < 2; ++ks) {
                h16x8 bk = *(const h16x8*)&Ks[(nt * 16 + (lane & 15)) * 72 + ks * 32 + (lane >> 4) * 8];
                accs[nt] = __builtin_amdgcn_mfma_f32_16x16x32_f16(aq[ks], bk, accs[nt], 0, 0, 0);
            }
        }
#pragma unroll
        for (int j = 0; j < 4; ++j) {
            float v = fmaxf(fmaxf(accs[0][j], accs[1][j]), fmaxf(accs[2][j], accs[3][j]));
#pragma unroll
            for (int o = 1; o < 16; o <<= 1) v = fmaxf(v, __shfl_xor(v, o, 64));
            const float mn = fmaxf(m[j], v);
            const float scl = __expf(0.125f * (m[j] - mn));
            m[j] = mn;
            l[j] *= scl;
#pragma unroll
            for (int nt2 = 0; nt2 < 4; ++nt2) acco[nt2][j] *= scl;
            float ps = 0.f;
            const int prow = ((lane >> 4) << 2) + j;
#pragma unroll
            for (int nt = 0; nt < 4; ++nt) {
                const float p = __expf(0.125f * (accs[nt][j] - mn));
                ps += p;
                Ps[w * 16 * 72 + prow * 72 + nt * 16 + (lane & 15)] = (_Float16)p;
            }
#pragma unroll
            for (int o = 1; o < 16; o <<= 1) ps += __shfl_xor(ps, o, 64);
            l[j] += ps;
        }
        __syncthreads();
#pragma unroll
        for (int ks2 = 0; ks2 < 2; ++ks2) {
            h16x8 pa = *(const h16x8*)&Ps[w * 16 * 72 + (lane & 15) * 72 + ks2 * 32 + (lane >> 4) * 8];
#pragma unroll
            for (int nt2 = 0; nt2 < 4; ++nt2) {
                h16x8 bv = *(const h16x8*)&Vs[(nt2 * 16 + (lane & 15)) * 72 + ks2 * 32 + (lane >> 4) * 8];
                acco[nt2] = __builtin_amdgcn_mfma_f32_16x16x32_f16(pa, bv, acco[nt2], 0, 0, 0);
            }
        }
    }
#pragma unroll
    for (int j = 0; j < 4; ++j) {
        const float inv = 1.0f / l[j];
        const size_t r = qrow0 + w * 16 + ((lane >> 4) << 2) + j;
#pragma unroll
        for (int nt2 = 0; nt2 < 4; ++nt2)
            Qb[r * 512 + col0 + nt2 * 16 + (lane & 15)] = (_Float16)(acco[nt2][j] * inv);
    }
}

// ---------------- poison fill ----------------
__global__ __launch_bounds__(256) void fill_poison(uint4* __restrict__ p, int n) {
    const uint4 v = {POISON, POISON, POISON, POISON};
    int i = blockIdx.x * 256 + threadIdx.x;
    const int st = gridDim.x * 256;
    for (; i < n; i += st) p[i] = v;
}

__device__ __forceinline__ unsigned long long poll2(const unsigned* p) {
    unsigned long long v = __hip_atomic_load((const unsigned long long*)p,
                                             __ATOMIC_RELAXED, __HIP_MEMORY_SCOPE_AGENT);
    while ((unsigned)v == POISON || (unsigned)(v >> 32) == POISON) {
        __builtin_amdgcn_s_sleep(1);
        v = __hip_atomic_load((const unsigned long long*)p,
                              __ATOMIC_RELAXED, __HIP_MEMORY_SCOPE_AGENT);
    }
    return v;
}

// ---------------- persistent single-layer RNN (256 blocks = 32 b x 8 slices) --------
// h = tanh(pre[t] + bhh + h[t-1] @ Whh^T). Whh slice pinned in VGPRs.
// Sync: poison-poll dataflow on hbuf itself (relaxed agent atomics).
// Also emits f16 copy of h for the next layer's MFMA input projection.
__global__ __launch_bounds__(256) void rnn_persist(const float* __restrict__ pre,
                                                   const float* __restrict__ Whh,
                                                   const float* __restrict__ bhh,
                                                   unsigned* __restrict__ hbuf,
                                                   _Float16* __restrict__ hbuf_h) {
    __shared__ float hl[512];
    __shared__ float part[64][17];
    const int tid = threadIdx.x;
    const int b = blockIdx.x & 31;
    const int sl = blockIdx.x >> 5;
    const int jq = tid & 15, kg = tid >> 4;
    const int jbase = sl * 64, k0 = kg * 32;
    const int j64 = tid & 63;

    // Whh slice -> VGPRs, pinned so the compiler cannot re-load per step
    f32x4 w[32];
#pragma unroll
    for (int jj = 0; jj < 4; ++jj)
#pragma unroll
        for (int c = 0; c < 8; ++c)
            w[jj * 8 + c] = *(const f32x4*)&Whh[(size_t)(jbase + jq * 4 + jj) * 512 + k0 + c * 4];
#pragma unroll
    for (int i = 0; i < 32; ++i) asm volatile("" : "+v"(w[i]));

    const float bj = bhh[jbase + j64];

    for (int t = 0; t < S; ++t) {
        // issue the pre load before the poll so it lands during the spin
        const float pv = pre[((size_t)t * 32 + b) * 512 + jbase + j64];
        float a0 = 0.f, a1 = 0.f, a2 = 0.f, a3 = 0.f;
        if (t > 0) {
            const unsigned long long v = poll2(hbuf + (size_t)(t - 1) * (B * H) + b * H + tid * 2);
            hl[tid * 2] = __uint_as_float((unsigned)v);
            hl[tid * 2 + 1] = __uint_as_float((unsigned)(v >> 32));
            __syncthreads();
            f32x4 hw[8];
#pragma unroll
            for (int c = 0; c < 8; ++c) hw[c] = *(const f32x4*)&hl[k0 + c * 4];
#pragma unroll
            for (int c = 0; c < 8; ++c) {
                a0 += w[0 * 8 + c][0] * hw[c][0] + w[0 * 8 + c][1] * hw[c][1]
                    + w[0 * 8 + c][2] * hw[c][2] + w[0 * 8 + c][3] * hw[c][3];
                a1 += w[1 * 8 + c][0] * hw[c][0] + w[1 * 8 + c][1] * hw[c][1]
                    + w[1 * 8 + c][2] * hw[c][2] + w[1 * 8 + c][3] * hw[c][3];
                a2 += w[2 * 8 + c][0] * hw[c][0] + w[2 * 8 + c][1] * hw[c][1]
                    + w[2 * 8 + c][2] * hw[c][2] + w[2 * 8 + c][3] * hw[c][3];
                a3 += w[3 * 8 + c][0] * hw[c][0] + w[3 * 8 + c][1] * hw[c][1]
                    + w[3 * 8 + c][2] * hw[c][2] + w[3 * 8 + c][3] * hw[c][3];
            }
        }
        part[jq * 4 + 0][kg] = a0;
        part[jq * 4 + 1][kg] = a1;
        part[jq * 4 + 2][kg] = a2;
        part[jq * 4 + 3][kg] = a3;
        __syncthreads();   // also: hl fully consumed
        if (tid < 64) {
            float s2 = 0.f;
#pragma unroll
            for (int i = 0; i < 16; ++i) s2 += part[tid][i];
            s2 += bj + pv;
            s2 = fminf(fmaxf(s2, -15.f), 15.f);
            const float ex = __expf(2.f * s2);
            const float hval = (ex - 1.f) / (ex + 1.f);
            const size_t idx = (size_t)t * (B * H) + b * H + jbase + tid;
            __hip_atomic_store(&hbuf[idx], __float_as_uint(hval),
                               __ATOMIC_RELAXED, __HIP_MEMORY_SCOPE_AGENT);
            hbuf_h[idx] = (_Float16)hval;
        }
        __syncthreads();   // part[] + hl protected before next iteration
    }
}

// ---------------- final FC: out[b] = h1[511][b,:] . Wfc[0,:] + bfc[0] ----------------
__global__ __launch_bounds__(64) void fc_out(const unsigned* __restrict__ hbits,
                                             const float* __restrict__ Wfc,
                                             const float* __restrict__ bfc,
                                             float* __restrict__ out) {
    int b = blockIdx.x;
    int t = threadIdx.x;
    float a = 0.f;
    for (int j = t; j < 512; j += 64) a += __uint_as_float(hbits[b * 512 + j]) * Wfc[j];
#pragma unroll
    for (int o = 32; o; o >>= 1) a += __shfl_down(a, o, 64);
    if (t == 0) out[b] = a + bfc[0];
}

extern "C" void kernel_launch(void* const* d_in, const int* in_sizes, int n_in,
                              void* d_out, int out_size, void* d_ws, size_t ws_size,
                              hipStream_t stream) {
    const float* x   = (const float*)d_in[0];
    const float* Wq  = (const float*)d_in[1];
    const float* bq  = (const float*)d_in[2];
    const float* Wk  = (const float*)d_in[3];
    const float* bk  = (const float*)d_in[4];
    const float* Wv  = (const float*)d_in[5];
    const float* bv  = (const float*)d_in[6];
    const float* Wo  = (const float*)d_in[7];
    const float* bo  = (const float*)d_in[8];
    const float* Wih = (const float*)d_in[9];
    const float* bih = (const float*)d_in[10];
    const float* Whh = (const float*)d_in[11];
    const float* bhh = (const float*)d_in[12];
    const float* Wfc = (const float*)d_in[13];
    const float* bfc = (const float*)d_in[14];
    float* out = (float*)d_out;
    char* base = (char*)d_ws;

    // [0,16M):   x_f16            -> h0 f32 slab [0,32M) after consumption
    // [32,48M):  Q_f16 -> ctx f16 -> h0_f16
    // [48,64M):  K_f16 -> atten_out f16 -\
    // [64,80M):  Vt f16                   -> h1 f32 slab [48,80M)
    // [80,112M): pre f32 (pre0, then pre1)
    // [112,115M): 6 f16 weights
    _Float16* xh   = (_Float16*)(base);
    unsigned* h0u  = (unsigned*)(base);
    _Float16* Qh   = (_Float16*)(base + ((size_t)32 << 20));
    _Float16* h0h  = (_Float16*)(base + ((size_t)32 << 20));
    _Float16* Kh   = (_Float16*)(base + ((size_t)48 << 20));
    unsigned* h1u  = (unsigned*)(base + ((size_t)48 << 20));
    _Float16* Vth  = (_Float16*)(base + ((size_t)64 << 20));
    float*    pre  = (float*)(base + ((size_t)80 << 20));
    _Float16* wgt  = (_Float16*)(base + ((size_t)112 << 20));
    const size_t WSZ = 512 * 512;

    cast_h<<<dim3(4096), dim3(256), 0, stream>>>(x, xh, (B * S * E) / 4);
    cast_h<<<dim3(256), dim3(256), 0, stream>>>(Wq, wgt + 0 * WSZ, WSZ / 4);
    cast_h<<<dim3(256), dim3(256), 0, stream>>>(Wk, wgt + 1 * WSZ, WSZ / 4);
    cast_h<<<dim3(256), dim3(256), 0, stream>>>(Wv, wgt + 2 * WSZ, WSZ / 4);
    cast_h<<<dim3(256), dim3(256), 0, stream>>>(Wo, wgt + 3 * WSZ, WSZ / 4);
    cast_h<<<dim3(256), dim3(256), 0, stream>>>(Wih, wgt + 4 * WSZ, WSZ / 4);
    cast_h<<<dim3(256), dim3(256), 0, stream>>>(Wih + WSZ, wgt + 5 * WSZ, WSZ / 4);

    const dim3 gg(4, 128), blk(256);
    gemm_mfma<1><<<gg, blk, 0, stream>>>(xh, wgt + 0 * WSZ, bq, Qh, B * S, E, E);
    gemm_mfma<1><<<gg, blk, 0, stream>>>(xh, wgt + 1 * WSZ, bk, Kh, B * S, E, E);
    gemm_mfma<2><<<gg, blk, 0, stream>>>(xh, wgt + 2 * WSZ, bv, Vth, B * S, E, E);
    attn_mfma<<<dim3(B * NH * 8), blk, 0, stream>>>(Qh, Kh, Vth);
    gemm_mfma<1><<<gg, blk, 0, stream>>>(Qh, wgt + 3 * WSZ, bo, Kh, B * S, E, E);
    gemm_mfma<3><<<gg, blk, 0, stream>>>(Kh, wgt + 4 * WSZ, bih, pre, B * S, H, E);

    // layer 0: poison h0 slab [0,32M) (xh consumed), run persistent RNN
    fill_poison<<<dim3(1024), blk, 0, stream>>>((uint4*)base, (32 << 20) / 16);
    rnn_persist<<<dim3(256), blk, 0, stream>>>(pre, Whh, bhh, h0u, h0h);
    // layer 1 input projection: pre1 = h0_f16 @ Wih1^T + bih1 (rows already t*32+b)
    gemm_mfma<0><<<gg, blk, 0, stream>>>(h0h, wgt + 5 * WSZ, bih + 512, pre, B * S, H, H);
    // layer 1: poison h1 slab [48,80M) (Kh/Vth consumed), run persistent RNN
    fill_poison<<<dim3(1024), blk, 0, stream>>>((uint4*)(base + ((size_t)48 << 20)),
                                                (32 << 20) / 16);
    rnn_persist<<<dim3(256), blk, 0, stream>>>(pre, Whh + WSZ, bhh + 512, h1u, h0h);
    fc_out<<<dim3(32), dim3(64), 0, stream>>>(h1u + (size_t)511 * B * H, Wfc, bfc, out);
}

// Round 8
// 1296.351 us; speedup vs baseline: 11.1246x; 1.0860x over previous
//
#include <hip/hip_runtime.h>
#include <hip/hip_fp16.h>

#define B 32
#define S 512
#define E 512
#define H 512
#define NH 8
#define HD 64
#define POISON 0x7FC0DEADu

typedef _Float16 h16x8 __attribute__((ext_vector_type(8)));
typedef _Float16 h16x4 __attribute__((ext_vector_type(4)));
typedef float f32x4 __attribute__((ext_vector_type(4)));

// ---------------- fp32 -> fp16 cast (vectorized, grid-stride) ----------------
__global__ __launch_bounds__(256) void cast_h(const float* __restrict__ src,
                                              _Float16* __restrict__ dst, int n4) {
    int i = blockIdx.x * 256 + threadIdx.x;
    const int stride = gridDim.x * 256;
    for (; i < n4; i += stride) {
        float4 v = ((const float4*)src)[i];
        h16x4 o;
        o[0] = (_Float16)v.x; o[1] = (_Float16)v.y;
        o[2] = (_Float16)v.z; o[3] = (_Float16)v.w;
        ((h16x4*)dst)[i] = o;
    }
}

// ---------------- MFMA GEMM: C[M,N] = A[M,K] @ W[N,K]^T + bias ----------------
// OMODE 0: f32 row-major. 1: f16 row-major. 2: f16 scattered to Vt[(b*8+h)*64+d][s].
// 3: f32 time-major scatter row r=b*512+s -> C[(s*32+b)*N+c].
template <int OMODE>
__global__ __launch_bounds__(256) void gemm_mfma(const _Float16* __restrict__ A,
                                                 const _Float16* __restrict__ W,
                                                 const float* __restrict__ bias,
                                                 void* __restrict__ Cout,
                                                 int M, int N, int K) {
    __shared__ __align__(16) _Float16 Als[128 * 32];
    __shared__ __align__(16) _Float16 Bls[128 * 32];
    const int tid = threadIdx.x;
    const int m0 = blockIdx.y * 128;
    const int n0 = blockIdx.x * 128;
    const int lane = tid & 63;
    const int w = tid >> 6;
    const int wm = w >> 1, wn = w & 1;
    f32x4 acc[4][4] = {};

    const int srow = tid >> 1;
    const int shalf = tid & 1;
    const _Float16* Ag = A + (size_t)(m0 + srow) * K + shalf * 16;
    const _Float16* Wg = W + (size_t)(n0 + srow) * K + shalf * 16;

    for (int k0 = 0; k0 < K; k0 += 32) {
        h16x8 a0 = *(const h16x8*)(Ag + k0);
        h16x8 a1 = *(const h16x8*)(Ag + k0 + 8);
        h16x8 b0 = *(const h16x8*)(Wg + k0);
        h16x8 b1 = *(const h16x8*)(Wg + k0 + 8);
        __syncthreads();
        *(h16x8*)&Als[srow * 32 + shalf * 16] = a0;
        *(h16x8*)&Als[srow * 32 + shalf * 16 + 8] = a1;
        *(h16x8*)&Bls[srow * 32 + shalf * 16] = b0;
        *(h16x8*)&Bls[srow * 32 + shalf * 16 + 8] = b1;
        __syncthreads();
        h16x8 af[4], bf[4];
#pragma unroll
        for (int mt = 0; mt < 4; ++mt)
            af[mt] = *(const h16x8*)&Als[(wm * 64 + mt * 16 + (lane & 15)) * 32 + (lane >> 4) * 8];
#pragma unroll
        for (int nt = 0; nt < 4; ++nt)
            bf[nt] = *(const h16x8*)&Bls[(wn * 64 + nt * 16 + (lane & 15)) * 32 + (lane >> 4) * 8];
#pragma unroll
        for (int mt = 0; mt < 4; ++mt)
#pragma unroll
            for (int nt = 0; nt < 4; ++nt)
                acc[mt][nt] = __builtin_amdgcn_mfma_f32_16x16x32_f16(af[mt], bf[nt], acc[mt][nt], 0, 0, 0);
    }

    float* Cf = (float*)Cout;
    _Float16* Ch = (_Float16*)Cout;
    const int colb = n0 + wn * 64 + (lane & 15);
    const int rowb = m0 + wm * 64 + ((lane >> 4) << 2);
#pragma unroll
    for (int mt = 0; mt < 4; ++mt) {
#pragma unroll
        for (int nt = 0; nt < 4; ++nt) {
            const int c = colb + nt * 16;
            const float bv = bias[c];
            if (OMODE == 2) {
                const int R0 = rowb + mt * 16;
                const int bb = R0 >> 9, s = R0 & 511, hh = c >> 6, d = c & 63;
                h16x4 pk;
#pragma unroll
                for (int j = 0; j < 4; ++j) pk[j] = (_Float16)(acc[mt][nt][j] + bv);
                *(h16x4*)&Ch[((size_t)(bb * 8 + hh) * 64 + d) * 512 + s] = pk;
            } else {
#pragma unroll
                for (int j = 0; j < 4; ++j) {
                    const int R = rowb + mt * 16 + j;
                    const float v = acc[mt][nt][j] + bv;
                    if (OMODE == 0) Cf[(size_t)R * N + c] = v;
                    else if (OMODE == 3) Cf[((size_t)(R & 511) * 32 + (R >> 9)) * N + c] = v;
                    else Ch[(size_t)R * N + c] = (_Float16)v;
                }
            }
        }
    }
}

// ---------------- MFMA flash attention: per (b, h, 64-row q-tile) ----------------
__global__ __launch_bounds__(256) void attn_mfma(_Float16* __restrict__ Qb,
                                                 const _Float16* __restrict__ Kb,
                                                 const _Float16* __restrict__ Vt) {
    __shared__ __align__(16) _Float16 Qs[64 * 72];
    __shared__ __align__(16) _Float16 Ks[64 * 72];
    __shared__ __align__(16) _Float16 Vs[64 * 72];
    __shared__ __align__(16) _Float16 Ps[4 * 16 * 72];
    const int tid = threadIdx.x;
    const int lane = tid & 63;
    const int w = tid >> 6;
    const int qt = blockIdx.x & 7;
    const int h = (blockIdx.x >> 3) & 7;
    const int b = blockIdx.x >> 6;
    const size_t qrow0 = (size_t)b * 512 + qt * 64;
    const int col0 = h * 64;

    {
        const int r = tid >> 2;
        const int c0 = (tid & 3) << 4;
        const _Float16* gq = &Qb[(qrow0 + r) * 512 + col0 + c0];
        *(h16x8*)&Qs[r * 72 + c0] = *(const h16x8*)(gq);
        *(h16x8*)&Qs[r * 72 + c0 + 8] = *(const h16x8*)(gq + 8);
    }
    __syncthreads();
    h16x8 aq[2];
#pragma unroll
    for (int ks = 0; ks < 2; ++ks)
        aq[ks] = *(const h16x8*)&Qs[(w * 16 + (lane & 15)) * 72 + ks * 32 + (lane >> 4) * 8];

    float m[4] = {-1e30f, -1e30f, -1e30f, -1e30f};
    float l[4] = {0.f, 0.f, 0.f, 0.f};
    f32x4 acco[4] = {};

    for (int kt = 0; kt < 8; ++kt) {
        __syncthreads();
        {
            const int r = tid >> 2;
            const int c0 = (tid & 3) << 4;
            const _Float16* gk = &Kb[((size_t)b * 512 + kt * 64 + r) * 512 + col0 + c0];
            *(h16x8*)&Ks[r * 72 + c0] = *(const h16x8*)(gk);
            *(h16x8*)&Ks[r * 72 + c0 + 8] = *(const h16x8*)(gk + 8);
            const _Float16* gv = &Vt[((size_t)(b * 8 + h) * 64 + r) * 512 + kt * 64 + c0];
            *(h16x8*)&Vs[r * 72 + c0] = *(const h16x8*)(gv);
            *(h16x8*)&Vs[r * 72 + c0 + 8] = *(const h16x8*)(gv + 8);
        }
        __syncthreads();
        f32x4 accs[4] = {};
#pragma unroll
        for (int nt = 0; nt < 4; ++nt) {
#pragma unroll
            for (int ks = 0; ks < 2; ++ks) {
                h16x8 bk = *(const h16x8*)&Ks[(nt * 16 + (lane & 15)) * 72 + ks * 32 + (lane >> 4) * 8];
                accs[nt] = __builtin_amdgcn_mfma_f32_16x16x32_f16(aq[ks], bk, accs[nt], 0, 0, 0);
            }
        }
#pragma unroll
        for (int j = 0; j < 4; ++j) {
            float v = fmaxf(fmaxf(accs[0][j], accs[1][j]), fmaxf(accs[2][j], accs[3][j]));
#pragma unroll
            for (int o = 1; o < 16; o <<= 1) v = fmaxf(v, __shfl_xor(v, o, 64));
            const float mn = fmaxf(m[j], v);
            const float scl = __expf(0.125f * (m[j] - mn));
            m[j] = mn;
            l[j] *= scl;
#pragma unroll
            for (int nt2 = 0; nt2 < 4; ++nt2) acco[nt2][j] *= scl;
            float ps = 0.f;
            const int prow = ((lane >> 4) << 2) + j;
#pragma unroll
            for (int nt = 0; nt < 4; ++nt) {
                const float p = __expf(0.125f * (accs[nt][j] - mn));
                ps += p;
                Ps[w * 16 * 72 + prow * 72 + nt * 16 + (lane & 15)] = (_Float16)p;
            }
#pragma unroll
            for (int o = 1; o < 16; o <<= 1) ps += __shfl_xor(ps, o, 64);
            l[j] += ps;
        }
        __syncthreads();
#pragma unroll
        for (int ks2 = 0; ks2 < 2; ++ks2) {
            h16x8 pa = *(const h16x8*)&Ps[w * 16 * 72 + (lane & 15) * 72 + ks2 * 32 + (lane >> 4) * 8];
#pragma unroll
            for (int nt2 = 0; nt2 < 4; ++nt2) {
                h16x8 bv = *(const h16x8*)&Vs[(nt2 * 16 + (lane & 15)) * 72 + ks2 * 32 + (lane >> 4) * 8];
                acco[nt2] = __builtin_amdgcn_mfma_f32_16x16x32_f16(pa, bv, acco[nt2], 0, 0, 0);
            }
        }
    }
#pragma unroll
    for (int j = 0; j < 4; ++j) {
        const float inv = 1.0f / l[j];
        const size_t r = qrow0 + w * 16 + ((lane >> 4) << 2) + j;
#pragma unroll
        for (int nt2 = 0; nt2 < 4; ++nt2)
            Qb[r * 512 + col0 + nt2 * 16 + (lane & 15)] = (_Float16)(acco[nt2][j] * inv);
    }
}

// ---------------- poison fill ----------------
__global__ __launch_bounds__(256) void fill_poison(uint4* __restrict__ p, int n) {
    const uint4 v = {POISON, POISON, POISON, POISON};
    int i = blockIdx.x * 256 + threadIdx.x;
    const int st = gridDim.x * 256;
    for (; i < n; i += st) p[i] = v;
}

__device__ __forceinline__ unsigned long long poll2(const unsigned* p) {
    unsigned long long v = __hip_atomic_load((const unsigned long long*)p,
                                             __ATOMIC_RELAXED, __HIP_MEMORY_SCOPE_AGENT);
    while ((unsigned)v == POISON || (unsigned)(v >> 32) == POISON) {
        __builtin_amdgcn_s_sleep(1);
        v = __hip_atomic_load((const unsigned long long*)p,
                              __ATOMIC_RELAXED, __HIP_MEMORY_SCOPE_AGENT);
    }
    return v;
}

// Weight tile in NAMED registers (no array => SROA cannot bail; asm pin => no remat).
#define DECLW(jj) f32x4 w##jj##_0, w##jj##_1, w##jj##_2, w##jj##_3, \
                        w##jj##_4, w##jj##_5, w##jj##_6, w##jj##_7
#define LOADW(jj) { const float* r_ = Whh + (size_t)(jbase + jq * 4 + jj) * 512 + k0; \
    w##jj##_0 = *(const f32x4*)&r_[0];  w##jj##_1 = *(const f32x4*)&r_[4];  \
    w##jj##_2 = *(const f32x4*)&r_[8];  w##jj##_3 = *(const f32x4*)&r_[12]; \
    w##jj##_4 = *(const f32x4*)&r_[16]; w##jj##_5 = *(const f32x4*)&r_[20]; \
    w##jj##_6 = *(const f32x4*)&r_[24]; w##jj##_7 = *(const f32x4*)&r_[28]; }
#define PINW(jj) asm volatile("" : "+v"(w##jj##_0), "+v"(w##jj##_1), "+v"(w##jj##_2), \
    "+v"(w##jj##_3), "+v"(w##jj##_4), "+v"(w##jj##_5), "+v"(w##jj##_6), "+v"(w##jj##_7))
#define ACCW(jj, c) a##jj += w##jj##_##c[0] * hw[c][0] + w##jj##_##c[1] * hw[c][1] \
                           + w##jj##_##c[2] * hw[c][2] + w##jj##_##c[3] * hw[c][3]
#define ACCROW(jj) ACCW(jj,0); ACCW(jj,1); ACCW(jj,2); ACCW(jj,3); \
                   ACCW(jj,4); ACCW(jj,5); ACCW(jj,6); ACCW(jj,7)

// ---------------- persistent single-layer RNN (256 blocks = 32 b x 8 slices) --------
__global__ __launch_bounds__(256) void rnn_persist(const float* __restrict__ pre,
                                                   const float* __restrict__ Whh,
                                                   const float* __restrict__ bhh,
                                                   unsigned* __restrict__ hbuf,
                                                   _Float16* __restrict__ hbuf_h) {
    __shared__ float hl[512];
    __shared__ float part[64][17];
    const int tid = threadIdx.x;
    const int b = blockIdx.x & 31;
    const int sl = blockIdx.x >> 5;
    const int jq = tid & 15, kg = tid >> 4;
    const int jbase = sl * 64, k0 = kg * 32;
    const int j64 = tid & 63;

    DECLW(0); DECLW(1); DECLW(2); DECLW(3);
    LOADW(0); LOADW(1); LOADW(2); LOADW(3);
    PINW(0); PINW(1); PINW(2); PINW(3);

    const float bj = bhh[jbase + j64];

    for (int t = 0; t < S; ++t) {
        // issue the pre load before the poll so it lands during the spin
        const float pv = pre[((size_t)t * 32 + b) * 512 + jbase + j64];
        float a0 = 0.f, a1 = 0.f, a2 = 0.f, a3 = 0.f;
        if (t > 0) {
            const unsigned long long v = poll2(hbuf + (size_t)(t - 1) * (B * H) + b * H + tid * 2);
            hl[tid * 2] = __uint_as_float((unsigned)v);
            hl[tid * 2 + 1] = __uint_as_float((unsigned)(v >> 32));
            __syncthreads();
            f32x4 hw[8];
#pragma unroll
            for (int c = 0; c < 8; ++c) hw[c] = *(const f32x4*)&hl[k0 + c * 4];
            ACCROW(0);
            ACCROW(1);
            ACCROW(2);
            ACCROW(3);
        }
        part[jq * 4 + 0][kg] = a0;
        part[jq * 4 + 1][kg] = a1;
        part[jq * 4 + 2][kg] = a2;
        part[jq * 4 + 3][kg] = a3;
        __syncthreads();   // also: hl fully consumed
        if (tid < 64) {
            float s2 = 0.f;
#pragma unroll
            for (int i = 0; i < 16; ++i) s2 += part[tid][i];
            s2 += bj + pv;
            s2 = fminf(fmaxf(s2, -15.f), 15.f);
            const float ex = __expf(2.f * s2);
            const float hval = (ex - 1.f) / (ex + 1.f);
            const size_t idx = (size_t)t * (B * H) + b * H + jbase + tid;
            __hip_atomic_store(&hbuf[idx], __float_as_uint(hval),
                               __ATOMIC_RELAXED, __HIP_MEMORY_SCOPE_AGENT);
            hbuf_h[idx] = (_Float16)hval;
        }
        __syncthreads();   // part[] + hl protected before next iteration
    }
}

// ---------------- final FC: out[b] = h1[511][b,:] . Wfc[0,:] + bfc[0] ----------------
__global__ __launch_bounds__(64) void fc_out(const unsigned* __restrict__ hbits,
                                             const float* __restrict__ Wfc,
                                             const float* __restrict__ bfc,
                                             float* __restrict__ out) {
    int b = blockIdx.x;
    int t = threadIdx.x;
    float a = 0.f;
    for (int j = t; j < 512; j += 64) a += __uint_as_float(hbits[b * 512 + j]) * Wfc[j];
#pragma unroll
    for (int o = 32; o; o >>= 1) a += __shfl_down(a, o, 64);
    if (t == 0) out[b] = a + bfc[0];
}

extern "C" void kernel_launch(void* const* d_in, const int* in_sizes, int n_in,
                              void* d_out, int out_size, void* d_ws, size_t ws_size,
                              hipStream_t stream) {
    const float* x   = (const float*)d_in[0];
    const float* Wq  = (const float*)d_in[1];
    const float* bq  = (const float*)d_in[2];
    const float* Wk  = (const float*)d_in[3];
    const float* bk  = (const float*)d_in[4];
    const float* Wv  = (const float*)d_in[5];
    const float* bv  = (const float*)d_in[6];
    const float* Wo  = (const float*)d_in[7];
    const float* bo  = (const float*)d_in[8];
    const float* Wih = (const float*)d_in[9];
    const float* bih = (const float*)d_in[10];
    const float* Whh = (const float*)d_in[11];
    const float* bhh = (const float*)d_in[12];
    const float* Wfc = (const float*)d_in[13];
    const float* bfc = (const float*)d_in[14];
    float* out = (float*)d_out;
    char* base = (char*)d_ws;

    _Float16* xh   = (_Float16*)(base);
    unsigned* h0u  = (unsigned*)(base);
    _Float16* Qh   = (_Float16*)(base + ((size_t)32 << 20));
    _Float16* h0h  = (_Float16*)(base + ((size_t)32 << 20));
    _Float16* Kh   = (_Float16*)(base + ((size_t)48 << 20));
    unsigned* h1u  = (unsigned*)(base + ((size_t)48 << 20));
    _Float16* Vth  = (_Float16*)(base + ((size_t)64 << 20));
    float*    pre  = (float*)(base + ((size_t)80 << 20));
    _Float16* wgt  = (_Float16*)(base + ((size_t)112 << 20));
    const size_t WSZ = 512 * 512;

    cast_h<<<dim3(4096), dim3(256), 0, stream>>>(x, xh, (B * S * E) / 4);
    cast_h<<<dim3(256), dim3(256), 0, stream>>>(Wq, wgt + 0 * WSZ, WSZ / 4);
    cast_h<<<dim3(256), dim3(256), 0, stream>>>(Wk, wgt + 1 * WSZ, WSZ / 4);
    cast_h<<<dim3(256), dim3(256), 0, stream>>>(Wv, wgt + 2 * WSZ, WSZ / 4);
    cast_h<<<dim3(256), dim3(256), 0, stream>>>(Wo, wgt + 3 * WSZ, WSZ / 4);
    cast_h<<<dim3(256), dim3(256), 0, stream>>>(Wih, wgt + 4 * WSZ, WSZ / 4);
    cast_h<<<dim3(256), dim3(256), 0, stream>>>(Wih + WSZ, wgt + 5 * WSZ, WSZ / 4);

    const dim3 gg(4, 128), blk(256);
    gemm_mfma<1><<<gg, blk, 0, stream>>>(xh, wgt + 0 * WSZ, bq, Qh, B * S, E, E);
    gemm_mfma<1><<<gg, blk, 0, stream>>>(xh, wgt + 1 * WSZ, bk, Kh, B * S, E, E);
    gemm_mfma<2><<<gg, blk, 0, stream>>>(xh, wgt + 2 * WSZ, bv, Vth, B * S, E, E);
    attn_mfma<<<dim3(B * NH * 8), blk, 0, stream>>>(Qh, Kh, Vth);
    gemm_mfma<1><<<gg, blk, 0, stream>>>(Qh, wgt + 3 * WSZ, bo, Kh, B * S, E, E);
    gemm_mfma<3><<<gg, blk, 0, stream>>>(Kh, wgt + 4 * WSZ, bih, pre, B * S, H, E);

    fill_poison<<<dim3(1024), blk, 0, stream>>>((uint4*)base, (32 << 20) / 16);
    rnn_persist<<<dim3(256), blk, 0, stream>>>(pre, Whh, bhh, h0u, h0h);
    gemm_mfma<0><<<gg, blk, 0, stream>>>(h0h, wgt + 5 * WSZ, bih + 512, pre, B * S, H, H);
    fill_poison<<<dim3(1024), blk, 0, stream>>>((uint4*)(base + ((size_t)48 << 20)),
                                                (32 << 20) / 16);
    rnn_persist<<<dim3(256), blk, 0, stream>>>(pre, Whh + WSZ, bhh + 512, h1u, h0h);
    fc_out<<<dim3(32), dim3(64), 0, stream>>>(h1u + (size_t)511 * B * H, Wfc, bfc, out);
}

// Round 9
// 1293.589 us; speedup vs baseline: 11.1484x; 1.0021x over previous
//
#include <hip/hip_runtime.h>
#include <hip/hip_fp16.h>

#define B 32
#define S 512
#define E 512
#define H 512
#define NH 8
#define HD 64
#define POISON 0x7FC0DEADu

typedef _Float16 h16x8 __attribute__((ext_vector_type(8)));
typedef _Float16 h16x4 __attribute__((ext_vector_type(4)));
typedef float f32x4 __attribute__((ext_vector_type(4)));

// ---------------- fp32 -> fp16 cast (vectorized, grid-stride) ----------------
__global__ __launch_bounds__(256) void cast_h(const float* __restrict__ src,
                                              _Float16* __restrict__ dst, int n4) {
    int i = blockIdx.x * 256 + threadIdx.x;
    const int stride = gridDim.x * 256;
    for (; i < n4; i += stride) {
        float4 v = ((const float4*)src)[i];
        h16x4 o;
        o[0] = (_Float16)v.x; o[1] = (_Float16)v.y;
        o[2] = (_Float16)v.z; o[3] = (_Float16)v.w;
        ((h16x4*)dst)[i] = o;
    }
}

// ---------------- MFMA GEMM: C[M,N] = A[M,K] @ W[N,K]^T + bias ----------------
// OMODE 0: f32 row-major. 1: f16 row-major. 2: f16 scattered to Vt[(b*8+h)*64+d][s].
// 3: f32 time-major scatter row r=b*512+s -> C[(s*32+b)*N+c].
template <int OMODE>
__global__ __launch_bounds__(256) void gemm_mfma(const _Float16* __restrict__ A,
                                                 const _Float16* __restrict__ W,
                                                 const float* __restrict__ bias,
                                                 void* __restrict__ Cout,
                                                 int M, int N, int K) {
    __shared__ __align__(16) _Float16 Als[128 * 32];
    __shared__ __align__(16) _Float16 Bls[128 * 32];
    const int tid = threadIdx.x;
    const int m0 = blockIdx.y * 128;
    const int n0 = blockIdx.x * 128;
    const int lane = tid & 63;
    const int w = tid >> 6;
    const int wm = w >> 1, wn = w & 1;
    f32x4 acc[4][4] = {};

    const int srow = tid >> 1;
    const int shalf = tid & 1;
    const _Float16* Ag = A + (size_t)(m0 + srow) * K + shalf * 16;
    const _Float16* Wg = W + (size_t)(n0 + srow) * K + shalf * 16;

    for (int k0 = 0; k0 < K; k0 += 32) {
        h16x8 a0 = *(const h16x8*)(Ag + k0);
        h16x8 a1 = *(const h16x8*)(Ag + k0 + 8);
        h16x8 b0 = *(const h16x8*)(Wg + k0);
        h16x8 b1 = *(const h16x8*)(Wg + k0 + 8);
        __syncthreads();
        *(h16x8*)&Als[srow * 32 + shalf * 16] = a0;
        *(h16x8*)&Als[srow * 32 + shalf * 16 + 8] = a1;
        *(h16x8*)&Bls[srow * 32 + shalf * 16] = b0;
        *(h16x8*)&Bls[srow * 32 + shalf * 16 + 8] = b1;
        __syncthreads();
        h16x8 af[4], bf[4];
#pragma unroll
        for (int mt = 0; mt < 4; ++mt)
            af[mt] = *(const h16x8*)&Als[(wm * 64 + mt * 16 + (lane & 15)) * 32 + (lane >> 4) * 8];
#pragma unroll
        for (int nt = 0; nt < 4; ++nt)
            bf[nt] = *(const h16x8*)&Bls[(wn * 64 + nt * 16 + (lane & 15)) * 32 + (lane >> 4) * 8];
#pragma unroll
        for (int mt = 0; mt < 4; ++mt)
#pragma unroll
            for (int nt = 0; nt < 4; ++nt)
                acc[mt][nt] = __builtin_amdgcn_mfma_f32_16x16x32_f16(af[mt], bf[nt], acc[mt][nt], 0, 0, 0);
    }

    float* Cf = (float*)Cout;
    _Float16* Ch = (_Float16*)Cout;
    const int colb = n0 + wn * 64 + (lane & 15);
    const int rowb = m0 + wm * 64 + ((lane >> 4) << 2);
#pragma unroll
    for (int mt = 0; mt < 4; ++mt) {
#pragma unroll
        for (int nt = 0; nt < 4; ++nt) {
            const int c = colb + nt * 16;
            const float bv = bias[c];
            if (OMODE == 2) {
                const int R0 = rowb + mt * 16;
                const int bb = R0 >> 9, s = R0 & 511, hh = c >> 6, d = c & 63;
                h16x4 pk;
#pragma unroll
                for (int j = 0; j < 4; ++j) pk[j] = (_Float16)(acc[mt][nt][j] + bv);
                *(h16x4*)&Ch[((size_t)(bb * 8 + hh) * 64 + d) * 512 + s] = pk;
            } else {
#pragma unroll
                for (int j = 0; j < 4; ++j) {
                    const int R = rowb + mt * 16 + j;
                    const float v = acc[mt][nt][j] + bv;
                    if (OMODE == 0) Cf[(size_t)R * N + c] = v;
                    else if (OMODE == 3) Cf[((size_t)(R & 511) * 32 + (R >> 9)) * N + c] = v;
                    else Ch[(size_t)R * N + c] = (_Float16)v;
                }
            }
        }
    }
}

// ---------------- MFMA flash attention: per (b, h, 64-row q-tile) ----------------
__global__ __launch_bounds__(256) void attn_mfma(_Float16* __restrict__ Qb,
                                                 const _Float16* __restrict__ Kb,
                                                 const _Float16* __restrict__ Vt) {
    __shared__ __align__(16) _Float16 Qs[64 * 72];
    __shared__ __align__(16) _Float16 Ks[64 * 72];
    __shared__ __align__(16) _Float16 Vs[64 * 72];
    __shared__ __align__(16) _Float16 Ps[4 * 16 * 72];
    const int tid = threadIdx.x;
    const int lane = tid & 63;
    const int w = tid >> 6;
    const int qt = blockIdx.x & 7;
    const int h = (blockIdx.x >> 3) & 7;
    const int b = blockIdx.x >> 6;
    const size_t qrow0 = (size_t)b * 512 + qt * 64;
    const int col0 = h * 64;

    {
        const int r = tid >> 2;
        const int c0 = (tid & 3) << 4;
        const _Float16* gq = &Qb[(qrow0 + r) * 512 + col0 + c0];
        *(h16x8*)&Qs[r * 72 + c0] = *(const h16x8*)(gq);
        *(h16x8*)&Qs[r * 72 + c0 + 8] = *(const h16x8*)(gq + 8);
    }
    __syncthreads();
    h16x8 aq[2];
#pragma unroll
    for (int ks = 0; ks < 2; ++ks)
        aq[ks] = *(const h16x8*)&Qs[(w * 16 + (lane & 15)) * 72 + ks * 32 + (lane >> 4) * 8];

    float m[4] = {-1e30f, -1e30f, -1e30f, -1e30f};
    float l[4] = {0.f, 0.f, 0.f, 0.f};
    f32x4 acco[4] = {};

    for (int kt = 0; kt < 8; ++kt) {
        __syncthreads();
        {
            const int r = tid >> 2;
            const int c0 = (tid & 3) << 4;
            const _Float16* gk = &Kb[((size_t)b * 512 + kt * 64 + r) * 512 + col0 + c0];
            *(h16x8*)&Ks[r * 72 + c0] = *(const h16x8*)(gk);
            *(h16x8*)&Ks[r * 72 + c0 + 8] = *(const h16x8*)(gk + 8);
            const _Float16* gv = &Vt[((size_t)(b * 8 + h) * 64 + r) * 512 + kt * 64 + c0];
            *(h16x8*)&Vs[r * 72 + c0] = *(const h16x8*)(gv);
            *(h16x8*)&Vs[r * 72 + c0 + 8] = *(const h16x8*)(gv + 8);
        }
        __syncthreads();
        f32x4 accs[4] = {};
#pragma unroll
        for (int nt = 0; nt < 4; ++nt) {
#pragma unroll
            for (int ks = 0; ks < 2; ++ks) {
                h16x8 bk = *(const h16x8*)&Ks[(nt * 16 + (lane & 15)) * 72 + ks * 32 + (lane >> 4) * 8];
                accs[nt] = __builtin_amdgcn_mfma_f32_16x16x32_f16(aq[ks], bk, accs[nt], 0, 0, 0);
            }
        }
#pragma unroll
        for (int j = 0; j < 4; ++j) {
            float v = fmaxf(fmaxf(accs[0][j], accs[1][j]), fmaxf(accs[2][j], accs[3][j]));
#pragma unroll
            for (int o = 1; o < 16; o <<= 1) v = fmaxf(v, __shfl_xor(v, o, 64));
            const float mn = fmaxf(m[j], v);
            const float scl = __expf(0.125f * (m[j] - mn));
            m[j] = mn;
            l[j] *= scl;
#pragma unroll
            for (int nt2 = 0; nt2 < 4; ++nt2) acco[nt2][j] *= scl;
            float ps = 0.f;
            const int prow = ((lane >> 4) << 2) + j;
#pragma unroll
            for (int nt = 0; nt < 4; ++nt) {
                const float p = __expf(0.125f * (accs[nt][j] - mn));
                ps += p;
                Ps[w * 16 * 72 + prow * 72 + nt * 16 + (lane & 15)] = (_Float16)p;
            }
#pragma unroll
            for (int o = 1; o < 16; o <<= 1) ps += __shfl_xor(ps, o, 64);
            l[j] += ps;
        }
        __syncthreads();
#pragma unroll
        for (int ks2 = 0; ks2 < 2; ++ks2) {
            h16x8 pa = *(const h16x8*)&Ps[w * 16 * 72 + (lane & 15) * 72 + ks2 * 32 + (lane >> 4) * 8];
#pragma unroll
            for (int nt2 = 0; nt2 < 4; ++nt2) {
                h16x8 bv = *(const h16x8*)&Vs[(nt2 * 16 + (lane & 15)) * 72 + ks2 * 32 + (lane >> 4) * 8];
                acco[nt2] = __builtin_amdgcn_mfma_f32_16x16x32_f16(pa, bv, acco[nt2], 0, 0, 0);
            }
        }
    }
#pragma unroll
    for (int j = 0; j < 4; ++j) {
        const float inv = 1.0f / l[j];
        const size_t r = qrow0 + w * 16 + ((lane >> 4) << 2) + j;
#pragma unroll
        for (int nt2 = 0; nt2 < 4; ++nt2)
            Qb[r * 512 + col0 + nt2 * 16 + (lane & 15)] = (_Float16)(acco[nt2][j] * inv);
    }
}

// ---------------- poison fill ----------------
__global__ __launch_bounds__(256) void fill_poison(uint4* __restrict__ p, int n) {
    const uint4 v = {POISON, POISON, POISON, POISON};
    int i = blockIdx.x * 256 + threadIdx.x;
    const int st = gridDim.x * 256;
    for (; i < n; i += st) p[i] = v;
}

__device__ __forceinline__ unsigned long long poll2(const unsigned* p) {
    unsigned long long v = __hip_atomic_load((const unsigned long long*)p,
                                             __ATOMIC_RELAXED, __HIP_MEMORY_SCOPE_AGENT);
    while ((unsigned)v == POISON || (unsigned)(v >> 32) == POISON) {
        __builtin_amdgcn_s_sleep(1);
        v = __hip_atomic_load((const unsigned long long*)p,
                              __ATOMIC_RELAXED, __HIP_MEMORY_SCOPE_AGENT);
    }
    return v;
}

// Weight tile in NAMED registers (no array => SROA cannot bail; asm pin => no remat).
#define DECLW(jj) f32x4 w##jj##_0, w##jj##_1, w##jj##_2, w##jj##_3, \
                        w##jj##_4, w##jj##_5, w##jj##_6, w##jj##_7
#define LOADW(jj) { const float* r_ = Whh + (size_t)(jbase + jq * 4 + jj) * 512 + k0; \
    w##jj##_0 = *(const f32x4*)&r_[0];  w##jj##_1 = *(const f32x4*)&r_[4];  \
    w##jj##_2 = *(const f32x4*)&r_[8];  w##jj##_3 = *(const f32x4*)&r_[12]; \
    w##jj##_4 = *(const f32x4*)&r_[16]; w##jj##_5 = *(const f32x4*)&r_[20]; \
    w##jj##_6 = *(const f32x4*)&r_[24]; w##jj##_7 = *(const f32x4*)&r_[28]; }
#define PINW(jj) asm volatile("" : "+v"(w##jj##_0), "+v"(w##jj##_1), "+v"(w##jj##_2), \
    "+v"(w##jj##_3), "+v"(w##jj##_4), "+v"(w##jj##_5), "+v"(w##jj##_6), "+v"(w##jj##_7))
#define ACCW(jj, c) a##jj += w##jj##_##c[0] * hw[c][0] + w##jj##_##c[1] * hw[c][1] \
                           + w##jj##_##c[2] * hw[c][2] + w##jj##_##c[3] * hw[c][3]
#define ACCROW(jj) ACCW(jj,0); ACCW(jj,1); ACCW(jj,2); ACCW(jj,3); \
                   ACCW(jj,4); ACCW(jj,5); ACCW(jj,6); ACCW(jj,7)

// ---------------- persistent single-layer RNN (256 blocks = 32 b x 8 slices) --------
// __launch_bounds__(256, 1): min 1 wave/EU -> VGPR budget ~512, so the pinned
// weight tile (128 VGPRs) stays register-resident instead of spilling to scratch.
__global__ __launch_bounds__(256, 1) void rnn_persist(const float* __restrict__ pre,
                                                      const float* __restrict__ Whh,
                                                      const float* __restrict__ bhh,
                                                      unsigned* __restrict__ hbuf,
                                                      _Float16* __restrict__ hbuf_h) {
    __shared__ float hl[512];
    __shared__ float part[64][17];
    const int tid = threadIdx.x;
    const int b = blockIdx.x & 31;
    const int sl = blockIdx.x >> 5;
    const int jq = tid & 15, kg = tid >> 4;
    const int jbase = sl * 64, k0 = kg * 32;
    const int j64 = tid & 63;

    DECLW(0); DECLW(1); DECLW(2); DECLW(3);
    LOADW(0); LOADW(1); LOADW(2); LOADW(3);
    PINW(0); PINW(1); PINW(2); PINW(3);

    const float bj = bhh[jbase + j64];

    for (int t = 0; t < S; ++t) {
        // issue the pre load before the poll so it lands during the spin
        const float pv = pre[((size_t)t * 32 + b) * 512 + jbase + j64];
        float a0 = 0.f, a1 = 0.f, a2 = 0.f, a3 = 0.f;
        if (t > 0) {
            const unsigned long long v = poll2(hbuf + (size_t)(t - 1) * (B * H) + b * H + tid * 2);
            hl[tid * 2] = __uint_as_float((unsigned)v);
            hl[tid * 2 + 1] = __uint_as_float((unsigned)(v >> 32));
            __syncthreads();
            f32x4 hw[8];
#pragma unroll
            for (int c = 0; c < 8; ++c) hw[c] = *(const f32x4*)&hl[k0 + c * 4];
            ACCROW(0);
            ACCROW(1);
            ACCROW(2);
            ACCROW(3);
        }
        part[jq * 4 + 0][kg] = a0;
        part[jq * 4 + 1][kg] = a1;
        part[jq * 4 + 2][kg] = a2;
        part[jq * 4 + 3][kg] = a3;
        __syncthreads();   // also: hl fully consumed
        if (tid < 64) {
            float s2 = 0.f;
#pragma unroll
            for (int i = 0; i < 16; ++i) s2 += part[tid][i];
            s2 += bj + pv;
            s2 = fminf(fmaxf(s2, -15.f), 15.f);
            const float ex = __expf(2.f * s2);
            const float hval = (ex - 1.f) / (ex + 1.f);
            const size_t idx = (size_t)t * (B * H) + b * H + jbase + tid;
            __hip_atomic_store(&hbuf[idx], __float_as_uint(hval),
                               __ATOMIC_RELAXED, __HIP_MEMORY_SCOPE_AGENT);
            hbuf_h[idx] = (_Float16)hval;
        }
        __syncthreads();   // part[] + hl protected before next iteration
    }
}

// ---------------- final FC: out[b] = h1[511][b,:] . Wfc[0,:] + bfc[0] ----------------
__global__ __launch_bounds__(64) void fc_out(const unsigned* __restrict__ hbits,
                                             const float* __restrict__ Wfc,
                                             const float* __restrict__ bfc,
                                             float* __restrict__ out) {
    int b = blockIdx.x;
    int t = threadIdx.x;
    float a = 0.f;
    for (int j = t; j < 512; j += 64) a += __uint_as_float(hbits[b * 512 + j]) * Wfc[j];
#pragma unroll
    for (int o = 32; o; o >>= 1) a += __shfl_down(a, o, 64);
    if (t == 0) out[b] = a + bfc[0];
}

extern "C" void kernel_launch(void* const* d_in, const int* in_sizes, int n_in,
                              void* d_out, int out_size, void* d_ws, size_t ws_size,
                              hipStream_t stream) {
    const float* x   = (const float*)d_in[0];
    const float* Wq  = (const float*)d_in[1];
    const float* bq  = (const float*)d_in[2];
    const float* Wk  = (const float*)d_in[3];
    const float* bk  = (const float*)d_in[4];
    const float* Wv  = (const float*)d_in[5];
    const float* bv  = (const float*)d_in[6];
    const float* Wo  = (const float*)d_in[7];
    const float* bo  = (const float*)d_in[8];
    const float* Wih = (const float*)d_in[9];
    const float* bih = (const float*)d_in[10];
    const float* Whh = (const float*)d_in[11];
    const float* bhh = (const float*)d_in[12];
    const float* Wfc = (const float*)d_in[13];
    const float* bfc = (const float*)d_in[14];
    float* out = (float*)d_out;
    char* base = (char*)d_ws;

    _Float16* xh   = (_Float16*)(base);
    unsigned* h0u  = (unsigned*)(base);
    _Float16* Qh   = (_Float16*)(base + ((size_t)32 << 20));
    _Float16* h0h  = (_Float16*)(base + ((size_t)32 << 20));
    _Float16* Kh   = (_Float16*)(base + ((size_t)48 << 20));
    unsigned* h1u  = (unsigned*)(base + ((size_t)48 << 20));
    _Float16* Vth  = (_Float16*)(base + ((size_t)64 << 20));
    float*    pre  = (float*)(base + ((size_t)80 << 20));
    _Float16* wgt  = (_Float16*)(base + ((size_t)112 << 20));
    const size_t WSZ = 512 * 512;

    cast_h<<<dim3(4096), dim3(256), 0, stream>>>(x, xh, (B * S * E) / 4);
    cast_h<<<dim3(256), dim3(256), 0, stream>>>(Wq, wgt + 0 * WSZ, WSZ / 4);
    cast_h<<<dim3(256), dim3(256), 0, stream>>>(Wk, wgt + 1 * WSZ, WSZ / 4);
    cast_h<<<dim3(256), dim3(256), 0, stream>>>(Wv, wgt + 2 * WSZ, WSZ / 4);
    cast_h<<<dim3(256), dim3(256), 0, stream>>>(Wo, wgt + 3 * WSZ, WSZ / 4);
    cast_h<<<dim3(256), dim3(256), 0, stream>>>(Wih, wgt + 4 * WSZ, WSZ / 4);
    cast_h<<<dim3(256), dim3(256), 0, stream>>>(Wih + WSZ, wgt + 5 * WSZ, WSZ / 4);

    const dim3 gg(4, 128), blk(256);
    gemm_mfma<1><<<gg, blk, 0, stream>>>(xh, wgt + 0 * WSZ, bq, Qh, B * S, E, E);
    gemm_mfma<1><<<gg, blk, 0, stream>>>(xh, wgt + 1 * WSZ, bk, Kh, B * S, E, E);
    gemm_mfma<2><<<gg, blk, 0, stream>>>(xh, wgt + 2 * WSZ, bv, Vth, B * S, E, E);
    attn_mfma<<<dim3(B * NH * 8), blk, 0, stream>>>(Qh, Kh, Vth);
    gemm_mfma<1><<<gg, blk, 0, stream>>>(Qh, wgt + 3 * WSZ, bo, Kh, B * S, E, E);
    gemm_mfma<3><<<gg, blk, 0, stream>>>(Kh, wgt + 4 * WSZ, bih, pre, B * S, H, E);

    fill_poison<<<dim3(1024), blk, 0, stream>>>((uint4*)base, (32 << 20) / 16);
    rnn_persist<<<dim3(256), blk, 0, stream>>>(pre, Whh, bhh, h0u, h0h);
    gemm_mfma<0><<<gg, blk, 0, stream>>>(h0h, wgt + 5 * WSZ, bih + 512, pre, B * S, H, H);
    fill_poison<<<dim3(1024), blk, 0, stream>>>((uint4*)(base + ((size_t)48 << 20)),
                                                (32 << 20) / 16);
    rnn_persist<<<dim3(256), blk, 0, stream>>>(pre, Whh + WSZ, bhh + 512, h1u, h0h);
    fc_out<<<dim3(32), dim3(64), 0, stream>>>(h1u + (size_t)511 * B * H, Wfc, bfc, out);
}